// Round 1
// baseline (63124.377 us; speedup 1.0000x reference)
//
#include <hip/hip_runtime.h>
#include <math.h>

// Problem constants (match reference)
#define BB   32
#define LSEQ 512
#define DD   512
#define HH   512
#define G2H  1024
#define K3H  1536

// ---------------------------------------------------------------------------
// Monotonic grid barrier: one agent-scope atomic add + spin per WG.
// Safe without cooperative launch because grid (256 WGs x 256 thr, ~41KB LDS)
// is far below device capacity -> all WGs are co-resident.
// __syncthreads() before arrival drains each wave's vmcnt (compiler emits
// full s_waitcnt before s_barrier), so all WG stores are in L2 before the
// RELEASE atomic publishes them (agent release = L2 writeback to MALL).
// ---------------------------------------------------------------------------
__device__ __forceinline__ void grid_barrier(unsigned* bar, unsigned target) {
  __syncthreads();
  if (threadIdx.x == 0) {
    __hip_atomic_fetch_add(bar, 1u, __ATOMIC_RELEASE, __HIP_MEMORY_SCOPE_AGENT);
    while (__hip_atomic_load(bar, __ATOMIC_ACQUIRE, __HIP_MEMORY_SCOPE_AGENT) < target) {
      __builtin_amdgcn_s_sleep(1);
    }
  }
  __syncthreads();
}

// ---------------------------------------------------------------------------
// RMSNorm: one 256-thread WG per row of 512.
// ---------------------------------------------------------------------------
__global__ __launch_bounds__(256)
void rmsnorm_kernel(const float* __restrict__ x, const float* __restrict__ w,
                    float* __restrict__ y)
{
  __shared__ float redl[256];
  const long row = blockIdx.x;
  const int t = threadIdx.x;
  const float* xr = x + row * DD;
  float v0 = xr[t], v1 = xr[t + 256];
  redl[t] = v0 * v0 + v1 * v1;
  __syncthreads();
  for (int off = 128; off > 0; off >>= 1) {
    if (t < off) redl[t] += redl[t + off];
    __syncthreads();
  }
  float scale = rsqrtf(redl[0] * (1.0f / 512.0f) + 1e-5f);
  float* yr = y + row * DD;
  yr[t]       = v0 * scale * w[t];
  yr[t + 256] = v1 * scale * w[t + 256];
}

// ---------------------------------------------------------------------------
// fp32 tiled GEMM: C[M,N] = A[M,K] @ B[K,N] (+ bias[n]), all row-major.
// 64x64 tile, BK=16, 256 threads, 4x4 microtile/thread, float4 I/O.
// ---------------------------------------------------------------------------
__global__ __launch_bounds__(256)
void gemm_fp32(const float* __restrict__ A, const float* __restrict__ B,
               const float* __restrict__ bias, float* __restrict__ C,
               int M, int N, int K)
{
  __shared__ float As[16][68];   // [k][m], +4 pad keeps float4 alignment
  __shared__ float Bs[16][64];   // [k][n]
  const int t  = threadIdx.x;
  const int tx = t & 15, ty = t >> 4;
  const long m0 = (long)blockIdx.x * 64;
  const long n0 = (long)blockIdx.y * 64;
  const int ar = t >> 2, ac = (t & 3) * 4;      // A-tile load: row ar, cols ac..ac+3
  const int bk = t >> 4, bn = (t & 15) * 4;     // B-tile load
  float acc[4][4] = {{0.f}};

  for (int k0 = 0; k0 < K; k0 += 16) {
    float4 av = *(const float4*)(A + (m0 + ar) * K + k0 + ac);
    float4 bv = *(const float4*)(B + (long)(k0 + bk) * N + n0 + bn);
    As[ac + 0][ar] = av.x; As[ac + 1][ar] = av.y;
    As[ac + 2][ar] = av.z; As[ac + 3][ar] = av.w;
    *(float4*)&Bs[bk][bn] = bv;
    __syncthreads();
#pragma unroll
    for (int kk = 0; kk < 16; ++kk) {
      float4 a = *(const float4*)&As[kk][ty * 4];
      float4 b = *(const float4*)&Bs[kk][tx * 4];
      acc[0][0] = fmaf(a.x, b.x, acc[0][0]); acc[0][1] = fmaf(a.x, b.y, acc[0][1]);
      acc[0][2] = fmaf(a.x, b.z, acc[0][2]); acc[0][3] = fmaf(a.x, b.w, acc[0][3]);
      acc[1][0] = fmaf(a.y, b.x, acc[1][0]); acc[1][1] = fmaf(a.y, b.y, acc[1][1]);
      acc[1][2] = fmaf(a.y, b.z, acc[1][2]); acc[1][3] = fmaf(a.y, b.w, acc[1][3]);
      acc[2][0] = fmaf(a.z, b.x, acc[2][0]); acc[2][1] = fmaf(a.z, b.y, acc[2][1]);
      acc[2][2] = fmaf(a.z, b.z, acc[2][2]); acc[2][3] = fmaf(a.z, b.w, acc[2][3]);
      acc[3][0] = fmaf(a.w, b.x, acc[3][0]); acc[3][1] = fmaf(a.w, b.y, acc[3][1]);
      acc[3][2] = fmaf(a.w, b.z, acc[3][2]); acc[3][3] = fmaf(a.w, b.w, acc[3][3]);
    }
    __syncthreads();
  }
  float4 bb = make_float4(0.f, 0.f, 0.f, 0.f);
  if (bias) bb = *(const float4*)(bias + n0 + tx * 4);
#pragma unroll
  for (int i = 0; i < 4; ++i) {
    float4 o;
    o.x = acc[i][0] + bb.x; o.y = acc[i][1] + bb.y;
    o.z = acc[i][2] + bb.z; o.w = acc[i][3] + bb.w;
    *(float4*)(C + (m0 + ty * 4 + i) * N + n0 + tx * 4) = o;
  }
}

// ---------------------------------------------------------------------------
// Persistent scan kernel. 256 WGs x 256 threads; WG w owns:
//   innov/c/K columns {2w, 2w+1}; g columns {2w,2w+1, 512+2w, 512+2w+1};
//   kmid columns {6w..6w+5}.
// Weight slices live in LDS (loaded once). State c is kept UNSCALED in
// global; the norm scale s[b] is recomputed by every WG during the full-c
// read of stage S1 (free: the read happens anyway for h@W_hh).
// 3 grid barriers per step.
// ---------------------------------------------------------------------------
__global__ __launch_bounds__(256)
void scan_kernel(const float* __restrict__ gx,
                 const float* __restrict__ Whh, const float* __restrict__ bhh,
                 const float* __restrict__ loglam,
                 const float* __restrict__ kW1, const float* __restrict__ kb1,
                 const float* __restrict__ kW2, const float* __restrict__ kb2,
                 float* __restrict__ c_glob, float* __restrict__ innov_glob,
                 float* __restrict__ kmid_glob, unsigned* __restrict__ bar,
                 float* __restrict__ hs)
{
  const int w   = blockIdx.x;      // 0..255
  const int tid = threadIdx.x;     // 0..255
  const int jz  = 2 * w;

  __shared__ float whh[4][HH];     // g cols: jz, jz+1, 512+jz, 512+jz+1 (k-major)
  __shared__ float kw1[6][HH];     // kmid cols 6w..6w+5
  __shared__ float kw2[2][K3H];    // K cols jz, jz+1
  __shared__ float red[1760];      // reduction scratch (S1:1280+160, S2:1536, S3:512)
  __shared__ float s_lds[32];
  __shared__ float A_lds[2][32];
  __shared__ float inv_own[2][32];
  __shared__ float M_own[2][32];
  __shared__ float c_own[2][32];
  __shared__ float consts[8];      // [0..1] A_base, [2..3] bhh_z, [4..5] bhh_m, [6..7] kb2
  __shared__ float kb1_l[6];

  // ---- one-time weight staging into LDS ----
  for (int i = tid; i < 4 * HH; i += 256) {
    int cc = i >> 9, k = i & (HH - 1);
    int gcol = (cc < 2) ? (jz + cc) : (HH + jz + (cc - 2));
    whh[cc][k] = Whh[(long)k * G2H + gcol];
  }
  for (int i = tid; i < 6 * HH; i += 256) {
    int cc = i / HH, k = i - cc * HH;
    kw1[cc][k] = kW1[(long)k * K3H + 6 * w + cc];
  }
  for (int i = tid; i < 2 * K3H; i += 256) {
    int cc = i & 1, k = i >> 1;
    kw2[cc][k] = kW2[(long)k * HH + jz + cc];
  }
  if (tid < 2) {
    consts[0 + tid] = 1.f - expf(loglam[jz + tid]);   // A_base
    consts[2 + tid] = bhh[jz + tid];
    consts[4 + tid] = bhh[HH + jz + tid];
    consts[6 + tid] = kb2[jz + tid];
  }
  if (tid < 6) kb1_l[tid] = kb1[6 * w + tid];
  if (tid < 64) {
    int cc = tid >> 5, b = tid & 31;
    A_lds[cc][b] = 0.f;
    c_own[cc][b] = 0.f;
    inv_own[cc][b] = 0.f;
    M_own[cc][b] = 0.f;
    c_glob[b * HH + jz + cc] = 0.f;   // zero-init state (ws is poisoned 0xAA)
  }
  unsigned gen = 0;
  grid_barrier(bar, (++gen) * 256u);  // all of c zeroed everywhere

  const int b8 = tid >> 3;   // batch row handled by this thread (8 thr/row)
  const int q8 = tid & 7;    // k-chunk

  for (int it = 0; it <= LSEQ; ++it) {
    // ---------------- S1: sumsq(c) + g = h@W_hh ; innov ----------------
    float ss = 0.f, g0 = 0.f, g1 = 0.f, g2 = 0.f, g3 = 0.f;
    {
      const float2* crow = (const float2*)(c_glob + (size_t)b8 * HH);
      const float2* w0 = (const float2*)&whh[0][0];
      const float2* w1 = (const float2*)&whh[1][0];
      const float2* w2 = (const float2*)&whh[2][0];
      const float2* w3 = (const float2*)&whh[3][0];
#pragma unroll 8
      for (int i2 = 0; i2 < 32; ++i2) {
        int j = q8 + 8 * i2;                 // float2 index; 8 lanes -> 64B line
        float2 cv = crow[j];
        float2 a0 = w0[j], a1 = w1[j], a2 = w2[j], a3 = w3[j];
        ss = fmaf(cv.x, cv.x, fmaf(cv.y, cv.y, ss));
        g0 = fmaf(cv.x, a0.x, fmaf(cv.y, a0.y, g0));
        g1 = fmaf(cv.x, a1.x, fmaf(cv.y, a1.y, g1));
        g2 = fmaf(cv.x, a2.x, fmaf(cv.y, a2.y, g2));
        g3 = fmaf(cv.x, a3.x, fmaf(cv.y, a3.y, g3));
      }
    }
    {
      int base = (b8 * 8 + q8) * 5;
      red[base + 0] = ss; red[base + 1] = g0; red[base + 2] = g1;
      red[base + 3] = g2; red[base + 4] = g3;
    }
    __syncthreads();
    if (tid < 160) {
      int bb = tid / 5, vv = tid - bb * 5;
      float a = 0.f;
#pragma unroll
      for (int q = 0; q < 8; ++q) a += red[(bb * 8 + q) * 5 + vv];
      red[1280 + bb * 5 + vv] = a;
    }
    __syncthreads();
    if (tid < 32) {
      float t2 = red[1280 + tid * 5];
      s_lds[tid] = fminf(1.f, 10.f / sqrtf(t2 + 1e-6f));
    }
    __syncthreads();
    // publish h = s*c for previous step's output
    if (it >= 1 && tid < 64) {
      int cc = tid >> 5, b = tid & 31;
      hs[((long)b * LSEQ + (it - 1)) * HH + jz + cc] = s_lds[b] * c_own[cc][b];
    }
    if (it == LSEQ) break;
    if (tid < 64) {
      int cc = tid >> 5, b = tid & 31;
      float s = s_lds[b];
      const float* gxrow = gx + ((long)b * LSEQ + it) * G2H;
      float gzv = red[1280 + b * 5 + 1 + cc] * s + gxrow[jz + cc] + consts[2 + cc];
      float gmv = red[1280 + b * 5 + 3 + cc] * s + gxrow[HH + jz + cc] + consts[4 + cc];
      float Mv = tanhf(gmv);
      float csld = s * c_own[cc][b];
      float iv = gzv - A_lds[cc][b] * csld - Mv;
      M_own[cc][b] = Mv;
      inv_own[cc][b] = iv;
      innov_glob[b * HH + jz + cc] = iv;
    }
    grid_barrier(bar, (++gen) * 256u);

    // ---------------- S2: kmid = gelu(innov @ kW1 + kb1) ----------------
    float p0 = 0.f, p1 = 0.f, p2 = 0.f, p3 = 0.f, p4 = 0.f, p5 = 0.f;
    {
      const float2* irow = (const float2*)(innov_glob + (size_t)b8 * HH);
      const float2* u0 = (const float2*)&kw1[0][0];
      const float2* u1 = (const float2*)&kw1[1][0];
      const float2* u2 = (const float2*)&kw1[2][0];
      const float2* u3 = (const float2*)&kw1[3][0];
      const float2* u4 = (const float2*)&kw1[4][0];
      const float2* u5 = (const float2*)&kw1[5][0];
#pragma unroll 8
      for (int i2 = 0; i2 < 32; ++i2) {
        int j = q8 + 8 * i2;
        float2 iv = irow[j];
        float2 a0 = u0[j], a1 = u1[j], a2 = u2[j];
        float2 a3 = u3[j], a4 = u4[j], a5 = u5[j];
        p0 = fmaf(iv.x, a0.x, fmaf(iv.y, a0.y, p0));
        p1 = fmaf(iv.x, a1.x, fmaf(iv.y, a1.y, p1));
        p2 = fmaf(iv.x, a2.x, fmaf(iv.y, a2.y, p2));
        p3 = fmaf(iv.x, a3.x, fmaf(iv.y, a3.y, p3));
        p4 = fmaf(iv.x, a4.x, fmaf(iv.y, a4.y, p4));
        p5 = fmaf(iv.x, a5.x, fmaf(iv.y, a5.y, p5));
      }
    }
    {
      int base = (b8 * 8 + q8) * 6;
      red[base + 0] = p0; red[base + 1] = p1; red[base + 2] = p2;
      red[base + 3] = p3; red[base + 4] = p4; red[base + 5] = p5;
    }
    __syncthreads();
    if (tid < 192) {
      int bb = tid / 6, cc = tid - bb * 6;
      float a = kb1_l[cc];
#pragma unroll
      for (int q = 0; q < 8; ++q) a += red[(bb * 8 + q) * 6 + cc];
      // exact gelu: x * 0.5 * (1 + erf(x/sqrt(2)))
      float gv = 0.5f * a * (1.f + erff(a * 0.7071067811865476f));
      kmid_glob[bb * K3H + 6 * w + cc] = gv;
    }
    grid_barrier(bar, (++gen) * 256u);

    // ---------------- S3: K = tanh(kmid @ kW2 + kb2)*0.5 ; c update ------
    float r0 = 0.f, r1 = 0.f;
    {
      const float2* krow = (const float2*)(kmid_glob + (size_t)b8 * K3H);
      const float2* v0 = (const float2*)&kw2[0][0];
      const float2* v1 = (const float2*)&kw2[1][0];
#pragma unroll 8
      for (int i2 = 0; i2 < 96; ++i2) {
        int j = q8 + 8 * i2;
        float2 kv = krow[j];
        float2 a0 = v0[j], a1 = v1[j];
        r0 = fmaf(kv.x, a0.x, fmaf(kv.y, a0.y, r0));
        r1 = fmaf(kv.x, a1.x, fmaf(kv.y, a1.y, r1));
      }
    }
    {
      int base = (b8 * 8 + q8) * 2;
      red[base + 0] = r0; red[base + 1] = r1;
    }
    __syncthreads();
    if (tid < 64) {
      int bb = tid >> 1, cc = tid & 1;
      float a = consts[6 + cc];
#pragma unroll
      for (int q = 0; q < 8; ++q) a += red[(bb * 8 + q) * 2 + cc];
      float Kv = tanhf(a) * 0.5f;
      float An = consts[0 + cc] * (1.f - Kv * Kv);
      float csld = s_lds[bb] * c_own[cc][bb];
      float cn = An * csld + Kv * inv_own[cc][bb] + M_own[cc][bb];
      A_lds[cc][bb] = An;
      c_own[cc][bb] = cn;
      c_glob[bb * HH + jz + cc] = cn;   // unscaled; consumers apply s next step
    }
    grid_barrier(bar, (++gen) * 256u);
  }
}

// ---------------------------------------------------------------------------
// Host-side orchestration. Workspace layout (bytes):
//   [0, 32M)    xn  (also reused as hs after gx GEMM)
//   [32M, 96M)  gx
//   [96M,128M)  xmid (layer-1 output)
//   [128M, ..)  c(64KB) | innov(64KB) | kmid(192KB) | barrier counter(4B)
// Peak ~128.4 MB.
// ---------------------------------------------------------------------------
extern "C" void kernel_launch(void* const* d_in, const int* in_sizes, int n_in,
                              void* d_out, int out_size, void* d_ws, size_t ws_size,
                              hipStream_t stream) {
  const float* x      = (const float*)d_in[0];
  const float* norm_w = (const float*)d_in[1];
  const float* W_ih   = (const float*)d_in[2];
  const float* b_ih   = (const float*)d_in[3];
  const float* W_hh   = (const float*)d_in[4];
  const float* b_hh   = (const float*)d_in[5];
  const float* loglam = (const float*)d_in[6];
  const float* kW1    = (const float*)d_in[7];
  const float* kb1    = (const float*)d_in[8];
  const float* kW2    = (const float*)d_in[9];
  const float* kb2    = (const float*)d_in[10];
  const float* Wo     = (const float*)d_in[11];
  float* out = (float*)d_out;

  char* ws = (char*)d_ws;
  float* xn   = (float*)(ws);
  float* gxb  = (float*)(ws + (size_t)33554432);
  float* xmid = (float*)(ws + (size_t)100663296);
  float* cbuf = (float*)(ws + (size_t)134217728);
  float* ibuf = cbuf + BB * HH;          // 16384 floats
  float* kbuf = ibuf + BB * HH;
  unsigned* bar = (unsigned*)(kbuf + BB * K3H);
  float* hs = xn;                        // reuse: xn dead after gx GEMM

  for (int l = 0; l < 2; ++l) {
    const float* xin = l ? (const float*)xmid : x;
    float* cout = l ? out : xmid;

    rmsnorm_kernel<<<BB * LSEQ, 256, 0, stream>>>(xin, norm_w, xn);

    gemm_fp32<<<dim3(256, 16), 256, 0, stream>>>(
        xn, W_ih + (size_t)l * DD * G2H, b_ih + (size_t)l * G2H, gxb,
        BB * LSEQ, G2H, DD);

    hipMemsetAsync(bar, 0, sizeof(unsigned), stream);
    scan_kernel<<<256, 256, 0, stream>>>(
        gxb,
        W_hh + (size_t)l * HH * G2H, b_hh + (size_t)l * G2H,
        loglam + (size_t)l * HH,
        kW1 + (size_t)l * HH * K3H, kb1 + (size_t)l * K3H,
        kW2 + (size_t)l * K3H * HH, kb2 + (size_t)l * HH,
        cbuf, ibuf, kbuf, bar, hs);

    gemm_fp32<<<dim3(256, 8), 256, 0, stream>>>(
        hs, Wo + (size_t)l * HH * DD, nullptr, cout,
        BB * LSEQ, DD, HH);
  }
}

// Round 2
// 56155.438 us; speedup vs baseline: 1.1241x; 1.1241x over previous
//
#include <hip/hip_runtime.h>
#include <math.h>

// Problem constants (match reference)
#define BB   32
#define LSEQ 512
#define DD   512
#define HH   512
#define G2H  1024
#define K3H  1536

// Scan partitioning: 2 independent groups x 128 WGs. Group g owns batch rows
// 16g..16g+15 (rows are independent across groups -> no inter-group sync).
// WG (member w in 0..127) owns c/innov/K cols jz=4w..4w+3, g-cols {jz..jz+3,
// 512+jz..512+jz+3}, kmid cols jm=12w..12w+11. 1024 threads = 16 waves; wave r
// handles batch row 16g+r end-to-end. All matvec reductions are in-register
// shuffle trees; recurrent per-(row,col) state lives in lane registers.
#define NGROUP 2
#define GW     128   // WGs per group
#define RPG    16    // rows per group
#define NCOLS  4     // c cols per WG
#define NKM    12    // kmid cols per WG

// ---------------------------------------------------------------------------
// Flag-based group barrier (width GW). Each member release-stores its own
// generation counter (distinct addresses -> no RMW serialization); threads
// 0..GW-1 (waves 0-1) each poll one flag. Monotonic generations, no reset.
// __syncthreads() before arrival drains all waves' vmcnt so the WG's global
// stores are visible before the release-store publishes them.
// ---------------------------------------------------------------------------
__device__ __forceinline__ void group_barrier(unsigned* f, int member,
                                              unsigned gen, int tid) {
  __syncthreads();
  if (tid < GW) {
    if (tid == 0)
      __hip_atomic_store(&f[member], gen, __ATOMIC_RELEASE, __HIP_MEMORY_SCOPE_AGENT);
    while (__hip_atomic_load(&f[tid], __ATOMIC_ACQUIRE, __HIP_MEMORY_SCOPE_AGENT) < gen)
      __builtin_amdgcn_s_sleep(4);
  }
  __syncthreads();
}

// In-register shuffle reduction trees over the 64-lane wave.
// TreeC<M>: compress M accumulators so a[0] holds the partial sum for
// col = lane & (M-1) (low col bit binds to low lane bit first).
template<int M> struct TreeC {
  static __device__ __forceinline__ void run(float* a, int lane, int d) {
    const bool hi = (lane & d) != 0;
#pragma unroll
    for (int i = 0; i < M / 2; ++i) {
      float mine  = hi ? a[2 * i + 1] : a[2 * i];
      float yours = hi ? a[2 * i]     : a[2 * i + 1];
      a[i] = mine + __shfl_xor(yours, d, 64);
    }
    TreeC<M / 2>::run(a, lane, d << 1);
  }
};
template<> struct TreeC<1> {
  static __device__ __forceinline__ void run(float*, int, int) {}
};

template<int M>
__device__ __forceinline__ float tree_reduce(float* a, int lane) {
  TreeC<M>::run(a, lane, 1);
  float v = a[0];
#pragma unroll
  for (int d = M; d <= 32; d <<= 1) v += __shfl_xor(v, d, 64);
  return v;  // total over 64 lanes for col = lane & (M-1)
}

__device__ __forceinline__ float allreduce64(float v) {
#pragma unroll
  for (int d = 1; d <= 32; d <<= 1) v += __shfl_xor(v, d, 64);
  return v;
}

__device__ __forceinline__ float dot4(float4 a, float4 b) {
  return fmaf(a.x, b.x, fmaf(a.y, b.y, fmaf(a.z, b.z, a.w * b.w)));
}

// ---------------------------------------------------------------------------
// RMSNorm: one 256-thread WG per row of 512.
// ---------------------------------------------------------------------------
__global__ __launch_bounds__(256)
void rmsnorm_kernel(const float* __restrict__ x, const float* __restrict__ w,
                    float* __restrict__ y)
{
  __shared__ float redl[256];
  const long row = blockIdx.x;
  const int t = threadIdx.x;
  const float* xr = x + row * DD;
  float v0 = xr[t], v1 = xr[t + 256];
  redl[t] = v0 * v0 + v1 * v1;
  __syncthreads();
  for (int off = 128; off > 0; off >>= 1) {
    if (t < off) redl[t] += redl[t + off];
    __syncthreads();
  }
  float scale = rsqrtf(redl[0] * (1.0f / 512.0f) + 1e-5f);
  float* yr = y + row * DD;
  yr[t]       = v0 * scale * w[t];
  yr[t + 256] = v1 * scale * w[t + 256];
}

// ---------------------------------------------------------------------------
// fp32 tiled GEMM: C[M,N] = A[M,K] @ B[K,N] (+ bias[n]), all row-major.
// ---------------------------------------------------------------------------
__global__ __launch_bounds__(256)
void gemm_fp32(const float* __restrict__ A, const float* __restrict__ B,
               const float* __restrict__ bias, float* __restrict__ C,
               int M, int N, int K)
{
  __shared__ float As[16][68];
  __shared__ float Bs[16][64];
  const int t  = threadIdx.x;
  const int tx = t & 15, ty = t >> 4;
  const long m0 = (long)blockIdx.x * 64;
  const long n0 = (long)blockIdx.y * 64;
  const int ar = t >> 2, ac = (t & 3) * 4;
  const int bk = t >> 4, bn = (t & 15) * 4;
  float acc[4][4] = {{0.f}};

  for (int k0 = 0; k0 < K; k0 += 16) {
    float4 av = *(const float4*)(A + (m0 + ar) * K + k0 + ac);
    float4 bv = *(const float4*)(B + (long)(k0 + bk) * N + n0 + bn);
    As[ac + 0][ar] = av.x; As[ac + 1][ar] = av.y;
    As[ac + 2][ar] = av.z; As[ac + 3][ar] = av.w;
    *(float4*)&Bs[bk][bn] = bv;
    __syncthreads();
#pragma unroll
    for (int kk = 0; kk < 16; ++kk) {
      float4 a = *(const float4*)&As[kk][ty * 4];
      float4 b = *(const float4*)&Bs[kk][tx * 4];
      acc[0][0] = fmaf(a.x, b.x, acc[0][0]); acc[0][1] = fmaf(a.x, b.y, acc[0][1]);
      acc[0][2] = fmaf(a.x, b.z, acc[0][2]); acc[0][3] = fmaf(a.x, b.w, acc[0][3]);
      acc[1][0] = fmaf(a.y, b.x, acc[1][0]); acc[1][1] = fmaf(a.y, b.y, acc[1][1]);
      acc[1][2] = fmaf(a.y, b.z, acc[1][2]); acc[1][3] = fmaf(a.y, b.w, acc[1][3]);
      acc[2][0] = fmaf(a.z, b.x, acc[2][0]); acc[2][1] = fmaf(a.z, b.y, acc[2][1]);
      acc[2][2] = fmaf(a.z, b.z, acc[2][2]); acc[2][3] = fmaf(a.z, b.w, acc[2][3]);
      acc[3][0] = fmaf(a.w, b.x, acc[3][0]); acc[3][1] = fmaf(a.w, b.y, acc[3][1]);
      acc[3][2] = fmaf(a.w, b.z, acc[3][2]); acc[3][3] = fmaf(a.w, b.w, acc[3][3]);
    }
    __syncthreads();
  }
  float4 bb = make_float4(0.f, 0.f, 0.f, 0.f);
  if (bias) bb = *(const float4*)(bias + n0 + tx * 4);
#pragma unroll
  for (int i = 0; i < 4; ++i) {
    float4 o;
    o.x = acc[i][0] + bb.x; o.y = acc[i][1] + bb.y;
    o.z = acc[i][2] + bb.z; o.w = acc[i][3] + bb.w;
    *(float4*)(C + (m0 + ty * 4 + i) * N + n0 + tx * 4) = o;
  }
}

// ---------------------------------------------------------------------------
// Persistent scan kernel, 256 WGs x 1024 threads.
// LDS = exactly 64 KB of weight slices, loaded once. No LDS scratch:
// reductions are register shuffle trees; state is in lane registers.
// ---------------------------------------------------------------------------
__global__ __launch_bounds__(1024)
void scan_kernel(const float* __restrict__ gx,
                 const float* __restrict__ Whh, const float* __restrict__ bhh,
                 const float* __restrict__ loglam,
                 const float* __restrict__ kW1, const float* __restrict__ kb1,
                 const float* __restrict__ kW2, const float* __restrict__ kb2,
                 float* __restrict__ c_glob, float* __restrict__ innov_glob,
                 float* __restrict__ kmid_glob, unsigned* __restrict__ flags,
                 float* __restrict__ hs)
{
  const int blk  = blockIdx.x;
  const int g    = blk & (NGROUP - 1);   // group: interleaved for XCD spread
  const int w    = blk >> 1;             // member 0..127
  const int tid  = threadIdx.x;
  const int wave = tid >> 6;             // 0..15 = local row
  const int lane = tid & 63;
  const int row  = g * RPG + wave;       // global batch row
  const int jz   = w * NCOLS;            // first owned c/innov/K col
  const int jm   = w * NKM;              // first owned kmid col

  // 64 KB static LDS: [c][k] layouts, k contiguous
  __shared__ float whh_z[NCOLS * HH];    //  8 KB
  __shared__ float whh_m[NCOLS * HH];    //  8 KB
  __shared__ float kw1s[NKM * HH];       // 24 KB
  __shared__ float kw2s[NCOLS * K3H];    // 24 KB

  for (int i = tid; i < NCOLS * HH; i += 1024) {
    int c = i >> 9, k = i & 511;
    whh_z[i] = Whh[(long)k * G2H + jz + c];
    whh_m[i] = Whh[(long)k * G2H + HH + jz + c];
  }
  for (int i = tid; i < NKM * HH; i += 1024) {
    int c = i >> 9, k = i & 511;
    kw1s[i] = kW1[(long)k * K3H + jm + c];
  }
  for (int i = tid; i < NCOLS * K3H; i += 1024) {
    int c = i / K3H, k = i - c * K3H;
    kw2s[i] = kW2[(long)k * HH + jz + c];
  }

  // persistent per-(row,col) state in lane registers (lanes 0..3 of each wave)
  float A_own = 0.f, c_own = 0.f, M_own = 0.f, inv_own = 0.f;
  float A_base = 0.f, bz = 0.f, bm = 0.f, kb2r = 0.f;
  if (lane < NCOLS) {
    A_base = 1.f - expf(loglam[jz + lane]);
    bz   = bhh[jz + lane];
    bm   = bhh[HH + jz + lane];
    kb2r = kb2[jz + lane];
    c_glob[(size_t)row * HH + jz + lane] = 0.f;   // zero-init state
  }
  const float kb1a = kb1[jm + (lane & 7)];
  const float kb1b = kb1[jm + 8 + (lane & 3)];

  unsigned* my_flags = flags + g * GW;
  unsigned gen = 0;
  group_barrier(my_flags, w, ++gen, tid);   // c zeros visible group-wide

  const float* crow = c_glob    + (size_t)row * HH;
  const float* irow = innov_glob + (size_t)row * HH;
  const float* krow = kmid_glob + (size_t)row * K3H;
  float s = 1.f;

  for (int it = 0; it <= LSEQ; ++it) {
    // ---- S1: sumsq(c_prev) -> s; g = h@W_hh; innov ----
    float gxz = 0.f, gxm = 0.f;
    if (it < LSEQ && lane < NCOLS) {
      const float* gxr = gx + ((size_t)row * LSEQ + it) * G2H;
      gxz = gxr[jz + lane];
      gxm = gxr[HH + jz + lane];
    }
    float4 c0 = *(const float4*)(crow + 4 * lane);
    float4 c1 = *(const float4*)(crow + 256 + 4 * lane);
    float ssp = dot4(c0, c0) + dot4(c1, c1);
    float a[2 * NCOLS];
#pragma unroll
    for (int c = 0; c < NCOLS; ++c) {
      float4 w0 = *(const float4*)(&whh_z[c * HH] + 4 * lane);
      float4 w1 = *(const float4*)(&whh_z[c * HH] + 256 + 4 * lane);
      a[c] = dot4(c0, w0) + dot4(c1, w1);
      float4 v0 = *(const float4*)(&whh_m[c * HH] + 4 * lane);
      float4 v1 = *(const float4*)(&whh_m[c * HH] + 256 + 4 * lane);
      a[NCOLS + c] = dot4(c0, v0) + dot4(c1, v1);
    }
    float gsum = tree_reduce<2 * NCOLS>(a, lane);     // lane&7: 0..3=z, 4..7=m
    float ss = allreduce64(ssp);
    s = fminf(1.f, 10.f * rsqrtf(ss + 1e-6f));
    float gm_other = __shfl(gsum, NCOLS + (lane & 3), 64);
    if (lane < NCOLS && it >= 1)
      hs[((size_t)row * LSEQ + (it - 1)) * HH + jz + lane] = s * c_own;
    if (it == LSEQ) break;
    if (lane < NCOLS) {
      float gz = gsum * s + gxz + bz;
      float gm = gm_other * s + gxm + bm;
      float Mv = tanhf(gm);
      float iv = gz - A_own * (s * c_own) - Mv;
      M_own = Mv; inv_own = iv;
      innov_glob[(size_t)row * HH + jz + lane] = iv;
    }
    group_barrier(my_flags, w, ++gen, tid);

    // ---- S2: kmid = gelu(innov @ kW1 + kb1), 12 owned cols ----
    float4 i0 = *(const float4*)(irow + 4 * lane);
    float4 i1 = *(const float4*)(irow + 256 + 4 * lane);
    float b1[8], b2[4];
#pragma unroll
    for (int c = 0; c < 8; ++c) {
      float4 w0 = *(const float4*)(&kw1s[c * HH] + 4 * lane);
      float4 w1 = *(const float4*)(&kw1s[c * HH] + 256 + 4 * lane);
      b1[c] = dot4(i0, w0) + dot4(i1, w1);
    }
#pragma unroll
    for (int c = 0; c < 4; ++c) {
      float4 w0 = *(const float4*)(&kw1s[(8 + c) * HH] + 4 * lane);
      float4 w1 = *(const float4*)(&kw1s[(8 + c) * HH] + 256 + 4 * lane);
      b2[c] = dot4(i0, w0) + dot4(i1, w1);
    }
    float k1 = tree_reduce<8>(b1, lane);   // col jm + (lane&7)
    float k2 = tree_reduce<4>(b2, lane);   // col jm + 8 + (lane&3)
    if (lane < 8) {
      float xg = k1 + kb1a;
      kmid_glob[(size_t)row * K3H + jm + lane] =
          0.5f * xg * (1.f + erff(xg * 0.7071067811865476f));
    }
    if (lane < 4) {
      float xg = k2 + kb1b;
      kmid_glob[(size_t)row * K3H + jm + 8 + lane] =
          0.5f * xg * (1.f + erff(xg * 0.7071067811865476f));
    }
    group_barrier(my_flags, w, ++gen, tid);

    // ---- S3: K = tanh(kmid @ kW2 + kb2)*0.5 ; c update ----
    float4 m0 = *(const float4*)(krow + 0 * 256 + 4 * lane);
    float4 m1 = *(const float4*)(krow + 1 * 256 + 4 * lane);
    float4 m2 = *(const float4*)(krow + 2 * 256 + 4 * lane);
    float4 m3 = *(const float4*)(krow + 3 * 256 + 4 * lane);
    float4 m4 = *(const float4*)(krow + 4 * 256 + 4 * lane);
    float4 m5 = *(const float4*)(krow + 5 * 256 + 4 * lane);
    float r[NCOLS];
#pragma unroll
    for (int c = 0; c < NCOLS; ++c) {
      const float* wc = &kw2s[c * K3H];
      float acc = dot4(m0, *(const float4*)(wc + 0 * 256 + 4 * lane));
      acc += dot4(m1, *(const float4*)(wc + 1 * 256 + 4 * lane));
      acc += dot4(m2, *(const float4*)(wc + 2 * 256 + 4 * lane));
      acc += dot4(m3, *(const float4*)(wc + 3 * 256 + 4 * lane));
      acc += dot4(m4, *(const float4*)(wc + 4 * 256 + 4 * lane));
      acc += dot4(m5, *(const float4*)(wc + 5 * 256 + 4 * lane));
      r[c] = acc;
    }
    float ksum = tree_reduce<NCOLS>(r, lane);   // col jz + (lane&3)
    if (lane < NCOLS) {
      float Kv = tanhf(ksum + kb2r) * 0.5f;
      float An = A_base * (1.f - Kv * Kv);
      float cn = An * (s * c_own) + Kv * inv_own + M_own;
      A_own = An; c_own = cn;
      c_glob[(size_t)row * HH + jz + lane] = cn;  // unscaled; s applied next step
    }
    group_barrier(my_flags, w, ++gen, tid);
  }
}

// ---------------------------------------------------------------------------
// Workspace layout (bytes):
//   [0, 32M)    xn  (reused as hs after gx GEMM)
//   [32M, 96M)  gx
//   [96M,128M)  xmid (layer-1 output)
//   [128M, ..)  c(64KB) | innov(64KB) | kmid(192KB) | flags(1KB)
// ---------------------------------------------------------------------------
extern "C" void kernel_launch(void* const* d_in, const int* in_sizes, int n_in,
                              void* d_out, int out_size, void* d_ws, size_t ws_size,
                              hipStream_t stream) {
  const float* x      = (const float*)d_in[0];
  const float* norm_w = (const float*)d_in[1];
  const float* W_ih   = (const float*)d_in[2];
  const float* b_ih   = (const float*)d_in[3];
  const float* W_hh   = (const float*)d_in[4];
  const float* b_hh   = (const float*)d_in[5];
  const float* loglam = (const float*)d_in[6];
  const float* kW1    = (const float*)d_in[7];
  const float* kb1    = (const float*)d_in[8];
  const float* kW2    = (const float*)d_in[9];
  const float* kb2    = (const float*)d_in[10];
  const float* Wo     = (const float*)d_in[11];
  float* out = (float*)d_out;

  char* ws = (char*)d_ws;
  float* xn   = (float*)(ws);
  float* gxb  = (float*)(ws + (size_t)33554432);
  float* xmid = (float*)(ws + (size_t)100663296);
  float* cbuf = (float*)(ws + (size_t)134217728);
  float* ibuf = cbuf + BB * HH;
  float* kbuf = ibuf + BB * HH;
  unsigned* flags = (unsigned*)(kbuf + BB * K3H);
  float* hs = xn;

  for (int l = 0; l < 2; ++l) {
    const float* xin = l ? (const float*)xmid : x;
    float* cout = l ? out : xmid;

    rmsnorm_kernel<<<BB * LSEQ, 256, 0, stream>>>(xin, norm_w, xn);

    gemm_fp32<<<dim3(256, 16), 256, 0, stream>>>(
        xn, W_ih + (size_t)l * DD * G2H, b_ih + (size_t)l * G2H, gxb,
        BB * LSEQ, G2H, DD);

    hipMemsetAsync(flags, 0, NGROUP * GW * sizeof(unsigned), stream);
    scan_kernel<<<NGROUP * GW, 1024, 0, stream>>>(
        gxb,
        W_hh + (size_t)l * HH * G2H, b_hh + (size_t)l * G2H,
        loglam + (size_t)l * HH,
        kW1 + (size_t)l * HH * K3H, kb1 + (size_t)l * K3H,
        kW2 + (size_t)l * K3H * HH, kb2 + (size_t)l * HH,
        cbuf, ibuf, kbuf, flags, hs);

    gemm_fp32<<<dim3(256, 8), 256, 0, stream>>>(
        hs, Wo + (size_t)l * HH * DD, nullptr, cout,
        BB * LSEQ, DD, HH);
  }
}

// Round 3
// 49559.808 us; speedup vs baseline: 1.2737x; 1.1331x over previous
//
#include <hip/hip_runtime.h>
#include <math.h>

// Problem constants (match reference)
#define BB   32
#define LSEQ 512
#define DD   512
#define HH   512
#define G2H  1024
#define K3H  1536

// Scan partitioning: 2 independent groups x 128 WGs; group g owns batch rows
// 16g..16g+15. WG (member w) owns c/innov/K cols jz=4w..4w+3 and kmid cols
// jm=12w..12w+11. WG = 256 threads = 4 waves; wave v processes 4 rows
// (16g+4v .. 16g+4v+3) so each LDS weight float4 is loaded once and FMA'd
// against 4 rows (4x LDS-traffic amortization vs 1 row/wave).
#define NGROUP 2
#define GW     128   // WGs per group
#define RPG    16    // rows per group
#define NCOLS  4     // c cols per WG
#define NKM    12    // kmid cols per WG
#define FPAD   16    // flag padding: 16 u32 = 64 B per flag line

// ---------------------------------------------------------------------------
// Group barrier v3. Arrival: one RELEASE store per WG to a PRIVATE 64B-padded
// flag (release = waitcnt + buffer_wbl2: publishes this XCD-L2's dirty data
// to MALL). Polling: RELAXED agent loads — these carry sc1 (read MALL
// directly, always fresh) but do NOT invalidate caches, unlike acquire loads
// which emit buffer_inv per iteration (the round-2 disaster). One acquire
// fence per wave afterwards invalidates stale L1/L2 exactly once.
// ---------------------------------------------------------------------------
__device__ __forceinline__ void group_barrier(unsigned* f, int member,
                                              unsigned gen, int tid) {
  __syncthreads();   // all waves' stores issued & vmcnt-drained (to L2)
  if (tid == 0)
    __hip_atomic_store(&f[member * FPAD], gen, __ATOMIC_RELEASE,
                       __HIP_MEMORY_SCOPE_AGENT);
  if (tid < GW) {
    while (__hip_atomic_load(&f[tid * FPAD], __ATOMIC_RELAXED,
                             __HIP_MEMORY_SCOPE_AGENT) < gen)
      __builtin_amdgcn_s_sleep(8);
  }
  __syncthreads();
  __builtin_amdgcn_fence(__ATOMIC_ACQUIRE, "agent");  // one inv per wave
}

// In-register shuffle reduction trees over the 64-lane wave.
template<int M> struct TreeC {
  static __device__ __forceinline__ void run(float* a, int lane, int d) {
    const bool hi = (lane & d) != 0;
#pragma unroll
    for (int i = 0; i < M / 2; ++i) {
      float mine  = hi ? a[2 * i + 1] : a[2 * i];
      float yours = hi ? a[2 * i]     : a[2 * i + 1];
      a[i] = mine + __shfl_xor(yours, d, 64);
    }
    TreeC<M / 2>::run(a, lane, d << 1);
  }
};
template<> struct TreeC<1> {
  static __device__ __forceinline__ void run(float*, int, int) {}
};

template<int M>
__device__ __forceinline__ float tree_reduce(float* a, int lane) {
  TreeC<M>::run(a, lane, 1);
  float v = a[0];
#pragma unroll
  for (int d = M; d <= 32; d <<= 1) v += __shfl_xor(v, d, 64);
  return v;  // total over 64 lanes for col = lane & (M-1)
}

__device__ __forceinline__ float allreduce64(float v) {
#pragma unroll
  for (int d = 1; d <= 32; d <<= 1) v += __shfl_xor(v, d, 64);
  return v;
}

__device__ __forceinline__ float dot4(float4 a, float4 b) {
  return fmaf(a.x, b.x, fmaf(a.y, b.y, fmaf(a.z, b.z, a.w * b.w)));
}

// ---------------------------------------------------------------------------
// RMSNorm: one 256-thread WG per row of 512.
// ---------------------------------------------------------------------------
__global__ __launch_bounds__(256)
void rmsnorm_kernel(const float* __restrict__ x, const float* __restrict__ w,
                    float* __restrict__ y)
{
  __shared__ float redl[256];
  const long row = blockIdx.x;
  const int t = threadIdx.x;
  const float* xr = x + row * DD;
  float v0 = xr[t], v1 = xr[t + 256];
  redl[t] = v0 * v0 + v1 * v1;
  __syncthreads();
  for (int off = 128; off > 0; off >>= 1) {
    if (t < off) redl[t] += redl[t + off];
    __syncthreads();
  }
  float scale = rsqrtf(redl[0] * (1.0f / 512.0f) + 1e-5f);
  float* yr = y + row * DD;
  yr[t]       = v0 * scale * w[t];
  yr[t + 256] = v1 * scale * w[t + 256];
}

// ---------------------------------------------------------------------------
// fp32 tiled GEMM: C[M,N] = A[M,K] @ B[K,N] (+ bias[n]), all row-major.
// ---------------------------------------------------------------------------
__global__ __launch_bounds__(256)
void gemm_fp32(const float* __restrict__ A, const float* __restrict__ B,
               const float* __restrict__ bias, float* __restrict__ C,
               int M, int N, int K)
{
  __shared__ float As[16][68];
  __shared__ float Bs[16][64];
  const int t  = threadIdx.x;
  const int tx = t & 15, ty = t >> 4;
  const long m0 = (long)blockIdx.x * 64;
  const long n0 = (long)blockIdx.y * 64;
  const int ar = t >> 2, ac = (t & 3) * 4;
  const int bk = t >> 4, bn = (t & 15) * 4;
  float acc[4][4] = {{0.f}};

  for (int k0 = 0; k0 < K; k0 += 16) {
    float4 av = *(const float4*)(A + (m0 + ar) * K + k0 + ac);
    float4 bv = *(const float4*)(B + (long)(k0 + bk) * N + n0 + bn);
    As[ac + 0][ar] = av.x; As[ac + 1][ar] = av.y;
    As[ac + 2][ar] = av.z; As[ac + 3][ar] = av.w;
    *(float4*)&Bs[bk][bn] = bv;
    __syncthreads();
#pragma unroll
    for (int kk = 0; kk < 16; ++kk) {
      float4 a = *(const float4*)&As[kk][ty * 4];
      float4 b = *(const float4*)&Bs[kk][tx * 4];
      acc[0][0] = fmaf(a.x, b.x, acc[0][0]); acc[0][1] = fmaf(a.x, b.y, acc[0][1]);
      acc[0][2] = fmaf(a.x, b.z, acc[0][2]); acc[0][3] = fmaf(a.x, b.w, acc[0][3]);
      acc[1][0] = fmaf(a.y, b.x, acc[1][0]); acc[1][1] = fmaf(a.y, b.y, acc[1][1]);
      acc[1][2] = fmaf(a.y, b.z, acc[1][2]); acc[1][3] = fmaf(a.y, b.w, acc[1][3]);
      acc[2][0] = fmaf(a.z, b.x, acc[2][0]); acc[2][1] = fmaf(a.z, b.y, acc[2][1]);
      acc[2][2] = fmaf(a.z, b.z, acc[2][2]); acc[2][3] = fmaf(a.z, b.w, acc[2][3]);
      acc[3][0] = fmaf(a.w, b.x, acc[3][0]); acc[3][1] = fmaf(a.w, b.y, acc[3][1]);
      acc[3][2] = fmaf(a.w, b.z, acc[3][2]); acc[3][3] = fmaf(a.w, b.w, acc[3][3]);
    }
    __syncthreads();
  }
  float4 bb = make_float4(0.f, 0.f, 0.f, 0.f);
  if (bias) bb = *(const float4*)(bias + n0 + tx * 4);
#pragma unroll
  for (int i = 0; i < 4; ++i) {
    float4 o;
    o.x = acc[i][0] + bb.x; o.y = acc[i][1] + bb.y;
    o.z = acc[i][2] + bb.z; o.w = acc[i][3] + bb.w;
    *(float4*)(C + (m0 + ty * 4 + i) * N + n0 + tx * 4) = o;
  }
}

// ---------------------------------------------------------------------------
// Persistent scan kernel, 256 WGs x 256 threads (4 waves x 4 rows each).
// 64 KB LDS of weight slices loaded once; reductions are shuffle trees.
// ---------------------------------------------------------------------------
__global__ __launch_bounds__(256)
void scan_kernel(const float* __restrict__ gx,
                 const float* __restrict__ Whh, const float* __restrict__ bhh,
                 const float* __restrict__ loglam,
                 const float* __restrict__ kW1, const float* __restrict__ kb1,
                 const float* __restrict__ kW2, const float* __restrict__ kb2,
                 float* __restrict__ c_glob, float* __restrict__ innov_glob,
                 float* __restrict__ kmid_glob, unsigned* __restrict__ flags,
                 float* __restrict__ hs)
{
  const int blk  = blockIdx.x;
  const int g    = blk & (NGROUP - 1);
  const int w    = blk >> 1;             // member 0..127
  const int tid  = threadIdx.x;
  const int wave = tid >> 6;             // 0..3
  const int lane = tid & 63;
  const int rowbase = g * RPG + 4 * wave;
  const int jz   = w * NCOLS;
  const int jm   = w * NKM;

  __shared__ float whh_z[NCOLS * HH];    //  8 KB
  __shared__ float whh_m[NCOLS * HH];    //  8 KB
  __shared__ float kw1s[NKM * HH];       // 24 KB
  __shared__ float kw2s[NCOLS * K3H];    // 24 KB

  for (int i = tid; i < NCOLS * HH; i += 256) {
    int c = i >> 9, k = i & 511;
    whh_z[i] = Whh[(long)k * G2H + jz + c];
    whh_m[i] = Whh[(long)k * G2H + HH + jz + c];
  }
  for (int i = tid; i < NKM * HH; i += 256) {
    int c = i >> 9, k = i & 511;
    kw1s[i] = kW1[(long)k * K3H + jm + c];
  }
  for (int i = tid; i < NCOLS * K3H; i += 256) {
    int c = i / K3H, k = i - c * K3H;
    kw2s[i] = kW2[(long)k * HH + jz + c];
  }

  // persistent per-(row,col) state; valid in lanes 0..3 (lane = col offset)
  float A_own[4] = {0.f, 0.f, 0.f, 0.f};
  float c_own[4] = {0.f, 0.f, 0.f, 0.f};
  float M_own[4] = {0.f, 0.f, 0.f, 0.f};
  float inv_own[4] = {0.f, 0.f, 0.f, 0.f};
  float sreg[4];
  float A_base = 0.f, bz = 0.f, bm = 0.f, kb2r = 0.f;
  if (lane < NCOLS) {
    A_base = 1.f - expf(loglam[jz + lane]);
    bz   = bhh[jz + lane];
    bm   = bhh[HH + jz + lane];
    kb2r = kb2[jz + lane];
#pragma unroll
    for (int i = 0; i < 4; ++i)
      c_glob[(size_t)(rowbase + i) * HH + jz + lane] = 0.f;
  }
  const float kb1a = kb1[jm + (lane & 7)];
  const float kb1b = kb1[jm + 8 + (lane & 3)];

  unsigned* my_flags = flags + g * GW * FPAD;
  unsigned gen = 0;
  group_barrier(my_flags, w, ++gen, tid);   // c zeros visible group-wide

  for (int it = 0; it <= LSEQ; ++it) {
    // gx prefetch (independent of barriers; scheduler hoists the loads)
    float gxz[4], gxm[4];
    if (it < LSEQ && lane < NCOLS) {
#pragma unroll
      for (int i = 0; i < 4; ++i) {
        const float* gxr = gx + ((size_t)(rowbase + i) * LSEQ + it) * G2H;
        gxz[i] = gxr[jz + lane];
        gxm[i] = gxr[HH + jz + lane];
      }
    }

    // ---- S1: sumsq(c_prev) -> s; g = h@W_hh; innov ----
    float az[NCOLS][4], am[NCOLS][4], ssp[4];
#pragma unroll
    for (int c = 0; c < NCOLS; ++c)
#pragma unroll
      for (int i = 0; i < 4; ++i) { az[c][i] = 0.f; am[c][i] = 0.f; }
#pragma unroll
    for (int i = 0; i < 4; ++i) ssp[i] = 0.f;

#pragma unroll
    for (int half = 0; half < 2; ++half) {
      float4 cv[4];
#pragma unroll
      for (int i = 0; i < 4; ++i)
        cv[i] = *(const float4*)(c_glob + (size_t)(rowbase + i) * HH +
                                 half * 256 + 4 * lane);
#pragma unroll
      for (int i = 0; i < 4; ++i) ssp[i] += dot4(cv[i], cv[i]);
#pragma unroll
      for (int c = 0; c < NCOLS; ++c) {
        float4 wz = *(const float4*)(&whh_z[c * HH + half * 256 + 4 * lane]);
        float4 wm = *(const float4*)(&whh_m[c * HH + half * 256 + 4 * lane]);
#pragma unroll
        for (int i = 0; i < 4; ++i) {
          az[c][i] += dot4(cv[i], wz);
          am[c][i] += dot4(cv[i], wm);
        }
      }
    }
#pragma unroll
    for (int i = 0; i < 4; ++i) {
      float a8[8];
#pragma unroll
      for (int c = 0; c < NCOLS; ++c) { a8[c] = az[c][i]; a8[4 + c] = am[c][i]; }
      float gsum = tree_reduce<8>(a8, lane);     // lane&7: 0..3=z, 4..7=m
      float ss = allreduce64(ssp[i]);
      float s = fminf(1.f, 10.f * rsqrtf(ss + 1e-6f));
      sreg[i] = s;
      float gmo = __shfl(gsum, NCOLS + (lane & 3), 64);
      if (it >= 1 && lane < NCOLS)
        hs[((size_t)(rowbase + i) * LSEQ + (it - 1)) * HH + jz + lane] =
            s * c_own[i];
      if (it < LSEQ && lane < NCOLS) {
        float gz = gsum * s + gxz[i] + bz;
        float gm = gmo * s + gxm[i] + bm;
        float Mv = tanhf(gm);
        float iv = gz - A_own[i] * (s * c_own[i]) - Mv;
        M_own[i] = Mv; inv_own[i] = iv;
        innov_glob[(size_t)(rowbase + i) * HH + jz + lane] = iv;
      }
    }
    if (it == LSEQ) break;
    group_barrier(my_flags, w, ++gen, tid);

    // ---- S2: kmid = gelu(innov @ kW1 + kb1), 12 owned cols ----
    float bacc[NKM][4];
#pragma unroll
    for (int c = 0; c < NKM; ++c)
#pragma unroll
      for (int i = 0; i < 4; ++i) bacc[c][i] = 0.f;
#pragma unroll
    for (int half = 0; half < 2; ++half) {
      float4 iv4[4];
#pragma unroll
      for (int i = 0; i < 4; ++i)
        iv4[i] = *(const float4*)(innov_glob + (size_t)(rowbase + i) * HH +
                                  half * 256 + 4 * lane);
#pragma unroll
      for (int c = 0; c < NKM; ++c) {
        float4 w1 = *(const float4*)(&kw1s[c * HH + half * 256 + 4 * lane]);
#pragma unroll
        for (int i = 0; i < 4; ++i) bacc[c][i] += dot4(iv4[i], w1);
      }
    }
#pragma unroll
    for (int i = 0; i < 4; ++i) {
      float b8[8], b4[4];
#pragma unroll
      for (int c = 0; c < 8; ++c) b8[c] = bacc[c][i];
#pragma unroll
      for (int c = 0; c < 4; ++c) b4[c] = bacc[8 + c][i];
      float k1 = tree_reduce<8>(b8, lane);   // col jm + (lane&7)
      float k2 = tree_reduce<4>(b4, lane);   // col jm + 8 + (lane&3)
      if (lane < 8) {
        float xg = k1 + kb1a;
        kmid_glob[(size_t)(rowbase + i) * K3H + jm + lane] =
            0.5f * xg * (1.f + erff(xg * 0.7071067811865476f));
      }
      if (lane < 4) {
        float xg = k2 + kb1b;
        kmid_glob[(size_t)(rowbase + i) * K3H + jm + 8 + lane] =
            0.5f * xg * (1.f + erff(xg * 0.7071067811865476f));
      }
    }
    group_barrier(my_flags, w, ++gen, tid);

    // ---- S3: K = tanh(kmid @ kW2 + kb2)*0.5 ; c update ----
    float racc[NCOLS][4];
#pragma unroll
    for (int c = 0; c < NCOLS; ++c)
#pragma unroll
      for (int i = 0; i < 4; ++i) racc[c][i] = 0.f;
#pragma unroll
    for (int chunk = 0; chunk < 6; ++chunk) {
      float4 mv[4];
#pragma unroll
      for (int i = 0; i < 4; ++i)
        mv[i] = *(const float4*)(kmid_glob + (size_t)(rowbase + i) * K3H +
                                 chunk * 256 + 4 * lane);
#pragma unroll
      for (int c = 0; c < NCOLS; ++c) {
        float4 w2 = *(const float4*)(&kw2s[c * K3H + chunk * 256 + 4 * lane]);
#pragma unroll
        for (int i = 0; i < 4; ++i) racc[c][i] += dot4(mv[i], w2);
      }
    }
#pragma unroll
    for (int i = 0; i < 4; ++i) {
      float r4[4];
#pragma unroll
      for (int c = 0; c < NCOLS; ++c) r4[c] = racc[c][i];
      float ksum = tree_reduce<4>(r4, lane);   // col jz + (lane&3)
      if (lane < NCOLS) {
        float Kv = tanhf(ksum + kb2r) * 0.5f;
        float An = A_base * (1.f - Kv * Kv);
        float cn = An * (sreg[i] * c_own[i]) + Kv * inv_own[i] + M_own[i];
        A_own[i] = An; c_own[i] = cn;
        c_glob[(size_t)(rowbase + i) * HH + jz + lane] = cn;
      }
    }
    group_barrier(my_flags, w, ++gen, tid);
  }
}

// ---------------------------------------------------------------------------
// Workspace layout (bytes):
//   [0, 32M)    xn  (reused as hs after gx GEMM)
//   [32M, 96M)  gx
//   [96M,128M)  xmid (layer-1 output)
//   [128M, ..)  c(64KB) | innov(64KB) | kmid(192KB) | flags(16KB padded)
// ---------------------------------------------------------------------------
extern "C" void kernel_launch(void* const* d_in, const int* in_sizes, int n_in,
                              void* d_out, int out_size, void* d_ws, size_t ws_size,
                              hipStream_t stream) {
  const float* x      = (const float*)d_in[0];
  const float* norm_w = (const float*)d_in[1];
  const float* W_ih   = (const float*)d_in[2];
  const float* b_ih   = (const float*)d_in[3];
  const float* W_hh   = (const float*)d_in[4];
  const float* b_hh   = (const float*)d_in[5];
  const float* loglam = (const float*)d_in[6];
  const float* kW1    = (const float*)d_in[7];
  const float* kb1    = (const float*)d_in[8];
  const float* kW2    = (const float*)d_in[9];
  const float* kb2    = (const float*)d_in[10];
  const float* Wo     = (const float*)d_in[11];
  float* out = (float*)d_out;

  char* ws = (char*)d_ws;
  float* xn   = (float*)(ws);
  float* gxb  = (float*)(ws + (size_t)33554432);
  float* xmid = (float*)(ws + (size_t)100663296);
  float* cbuf = (float*)(ws + (size_t)134217728);
  float* ibuf = cbuf + BB * HH;
  float* kbuf = ibuf + BB * HH;
  unsigned* flags = (unsigned*)(kbuf + BB * K3H);
  float* hs = xn;

  for (int l = 0; l < 2; ++l) {
    const float* xin = l ? (const float*)xmid : x;
    float* cout = l ? out : xmid;

    rmsnorm_kernel<<<BB * LSEQ, 256, 0, stream>>>(xin, norm_w, xn);

    gemm_fp32<<<dim3(256, 16), 256, 0, stream>>>(
        xn, W_ih + (size_t)l * DD * G2H, b_ih + (size_t)l * G2H, gxb,
        BB * LSEQ, G2H, DD);

    hipMemsetAsync(flags, 0, NGROUP * GW * FPAD * sizeof(unsigned), stream);
    scan_kernel<<<NGROUP * GW, 256, 0, stream>>>(
        gxb,
        W_hh + (size_t)l * HH * G2H, b_hh + (size_t)l * G2H,
        loglam + (size_t)l * HH,
        kW1 + (size_t)l * HH * K3H, kb1 + (size_t)l * K3H,
        kW2 + (size_t)l * K3H * HH, kb2 + (size_t)l * HH,
        cbuf, ibuf, kbuf, flags, hs);

    gemm_fp32<<<dim3(256, 8), 256, 0, stream>>>(
        hs, Wo + (size_t)l * HH * DD, nullptr, cout,
        BB * LSEQ, DD, HH);
  }
}

// Round 4
// 48248.260 us; speedup vs baseline: 1.3083x; 1.0272x over previous
//
#include <hip/hip_runtime.h>
#include <math.h>

// Problem constants (match reference)
#define BB   32
#define LSEQ 512
#define DD   512
#define HH   512
#define G2H  1024
#define K3H  1536

// Scan partitioning: 2 independent groups x 128 WGs; group g owns batch rows
// 16g..16g+15. WG (member w) owns c/innov/K cols jz=4w..4w+3 and kmid cols
// jm=12w..12w+11. WG = 256 threads = 4 waves; wave v processes 4 rows.
#define NGROUP 2
#define GW     128   // WGs per group
#define RPG    16    // rows per group
#define NCOLS  4     // c cols per WG
#define NKM    12    // kmid cols per WG
#define FPAD   16    // flag padding: 16 u32 = 64 B per flag line

// ---------------------------------------------------------------------------
// Group barrier v4 — master-aggregated (fixes the round-1..3 poll storm).
// Workers: one RELEASE store to a private padded flag (waitcnt+wbl2 publishes
// this XCD's dirty L2 to MALL), then ONE lane polls ONE shared "go" line with
// RELAXED loads (no cache maintenance per poll). Master (member 0): 128 lanes
// poll the 128 arrival flags (relaxed), then release-stores go=gen. Poll
// traffic ~20 GB/s total vs ~1.7 TB/s for the previous 128-poller-per-WG
// scheme that saturated the MALL and caused 10-40us/barrier with 2.7x
// variance. One acquire fence per wave after the barrier invalidates L1/L2
// once so subsequent normal vector loads see MALL data.
// ---------------------------------------------------------------------------
__device__ __forceinline__ void group_barrier(unsigned* arrive, unsigned* go,
                                              int member, unsigned gen, int tid) {
  __syncthreads();   // all 4 waves' data stores issued & vmcnt-drained (in L2)
  if (tid == 0)
    __hip_atomic_store(&arrive[member * FPAD], gen, __ATOMIC_RELEASE,
                       __HIP_MEMORY_SCOPE_AGENT);
  if (member == 0) {
    if (tid < GW) {
      while (__hip_atomic_load(&arrive[tid * FPAD], __ATOMIC_RELAXED,
                               __HIP_MEMORY_SCOPE_AGENT) < gen) { }
    }
    __syncthreads();             // all 128 arrivals observed collectively
    if (tid == 0)
      __hip_atomic_store(go, gen, __ATOMIC_RELEASE, __HIP_MEMORY_SCOPE_AGENT);
  } else {
    if (tid == 0) {
      while (__hip_atomic_load(go, __ATOMIC_RELAXED,
                               __HIP_MEMORY_SCOPE_AGENT) < gen) { }
    }
  }
  __syncthreads();
  __builtin_amdgcn_fence(__ATOMIC_ACQUIRE, "agent");  // one inv per wave
}

// In-register shuffle reduction trees over the 64-lane wave.
template<int M> struct TreeC {
  static __device__ __forceinline__ void run(float* a, int lane, int d) {
    const bool hi = (lane & d) != 0;
#pragma unroll
    for (int i = 0; i < M / 2; ++i) {
      float mine  = hi ? a[2 * i + 1] : a[2 * i];
      float yours = hi ? a[2 * i]     : a[2 * i + 1];
      a[i] = mine + __shfl_xor(yours, d, 64);
    }
    TreeC<M / 2>::run(a, lane, d << 1);
  }
};
template<> struct TreeC<1> {
  static __device__ __forceinline__ void run(float*, int, int) {}
};

template<int M>
__device__ __forceinline__ float tree_reduce(float* a, int lane) {
  TreeC<M>::run(a, lane, 1);
  float v = a[0];
#pragma unroll
  for (int d = M; d <= 32; d <<= 1) v += __shfl_xor(v, d, 64);
  return v;  // total over 64 lanes for col = lane & (M-1)
}

__device__ __forceinline__ float allreduce64(float v) {
#pragma unroll
  for (int d = 1; d <= 32; d <<= 1) v += __shfl_xor(v, d, 64);
  return v;
}

__device__ __forceinline__ float dot4(float4 a, float4 b) {
  return fmaf(a.x, b.x, fmaf(a.y, b.y, fmaf(a.z, b.z, a.w * b.w)));
}

// ---------------------------------------------------------------------------
// RMSNorm: one 256-thread WG per row of 512.
// ---------------------------------------------------------------------------
__global__ __launch_bounds__(256)
void rmsnorm_kernel(const float* __restrict__ x, const float* __restrict__ w,
                    float* __restrict__ y)
{
  __shared__ float redl[256];
  const long row = blockIdx.x;
  const int t = threadIdx.x;
  const float* xr = x + row * DD;
  float v0 = xr[t], v1 = xr[t + 256];
  redl[t] = v0 * v0 + v1 * v1;
  __syncthreads();
  for (int off = 128; off > 0; off >>= 1) {
    if (t < off) redl[t] += redl[t + off];
    __syncthreads();
  }
  float scale = rsqrtf(redl[0] * (1.0f / 512.0f) + 1e-5f);
  float* yr = y + row * DD;
  yr[t]       = v0 * scale * w[t];
  yr[t + 256] = v1 * scale * w[t + 256];
}

// ---------------------------------------------------------------------------
// fp32 tiled GEMM: C[M,N] = A[M,K] @ B[K,N] (+ bias[n]), all row-major.
// ---------------------------------------------------------------------------
__global__ __launch_bounds__(256)
void gemm_fp32(const float* __restrict__ A, const float* __restrict__ B,
               const float* __restrict__ bias, float* __restrict__ C,
               int M, int N, int K)
{
  __shared__ float As[16][68];
  __shared__ float Bs[16][64];
  const int t  = threadIdx.x;
  const int tx = t & 15, ty = t >> 4;
  const long m0 = (long)blockIdx.x * 64;
  const long n0 = (long)blockIdx.y * 64;
  const int ar = t >> 2, ac = (t & 3) * 4;
  const int bk = t >> 4, bn = (t & 15) * 4;
  float acc[4][4] = {{0.f}};

  for (int k0 = 0; k0 < K; k0 += 16) {
    float4 av = *(const float4*)(A + (m0 + ar) * K + k0 + ac);
    float4 bv = *(const float4*)(B + (long)(k0 + bk) * N + n0 + bn);
    As[ac + 0][ar] = av.x; As[ac + 1][ar] = av.y;
    As[ac + 2][ar] = av.z; As[ac + 3][ar] = av.w;
    *(float4*)&Bs[bk][bn] = bv;
    __syncthreads();
#pragma unroll
    for (int kk = 0; kk < 16; ++kk) {
      float4 a = *(const float4*)&As[kk][ty * 4];
      float4 b = *(const float4*)&Bs[kk][tx * 4];
      acc[0][0] = fmaf(a.x, b.x, acc[0][0]); acc[0][1] = fmaf(a.x, b.y, acc[0][1]);
      acc[0][2] = fmaf(a.x, b.z, acc[0][2]); acc[0][3] = fmaf(a.x, b.w, acc[0][3]);
      acc[1][0] = fmaf(a.y, b.x, acc[1][0]); acc[1][1] = fmaf(a.y, b.y, acc[1][1]);
      acc[1][2] = fmaf(a.y, b.z, acc[1][2]); acc[1][3] = fmaf(a.y, b.w, acc[1][3]);
      acc[2][0] = fmaf(a.z, b.x, acc[2][0]); acc[2][1] = fmaf(a.z, b.y, acc[2][1]);
      acc[2][2] = fmaf(a.z, b.z, acc[2][2]); acc[2][3] = fmaf(a.z, b.w, acc[2][3]);
      acc[3][0] = fmaf(a.w, b.x, acc[3][0]); acc[3][1] = fmaf(a.w, b.y, acc[3][1]);
      acc[3][2] = fmaf(a.w, b.z, acc[3][2]); acc[3][3] = fmaf(a.w, b.w, acc[3][3]);
    }
    __syncthreads();
  }
  float4 bb = make_float4(0.f, 0.f, 0.f, 0.f);
  if (bias) bb = *(const float4*)(bias + n0 + tx * 4);
#pragma unroll
  for (int i = 0; i < 4; ++i) {
    float4 o;
    o.x = acc[i][0] + bb.x; o.y = acc[i][1] + bb.y;
    o.z = acc[i][2] + bb.z; o.w = acc[i][3] + bb.w;
    *(float4*)(C + (m0 + ty * 4 + i) * N + n0 + tx * 4) = o;
  }
}

// ---------------------------------------------------------------------------
// Persistent scan kernel, 256 WGs x 256 threads (4 waves x 4 rows each).
// 64 KB LDS of weight slices loaded once; reductions are shuffle trees.
// ---------------------------------------------------------------------------
__global__ __launch_bounds__(256)
void scan_kernel(const float* __restrict__ gx,
                 const float* __restrict__ Whh, const float* __restrict__ bhh,
                 const float* __restrict__ loglam,
                 const float* __restrict__ kW1, const float* __restrict__ kb1,
                 const float* __restrict__ kW2, const float* __restrict__ kb2,
                 float* __restrict__ c_glob, float* __restrict__ innov_glob,
                 float* __restrict__ kmid_glob, unsigned* __restrict__ flags,
                 float* __restrict__ hs)
{
  const int blk  = blockIdx.x;
  const int g    = blk & (NGROUP - 1);
  const int w    = blk >> 1;             // member 0..127
  const int tid  = threadIdx.x;
  const int wave = tid >> 6;             // 0..3
  const int lane = tid & 63;
  const int rowbase = g * RPG + 4 * wave;
  const int jz   = w * NCOLS;
  const int jm   = w * NKM;

  __shared__ float whh_z[NCOLS * HH];    //  8 KB
  __shared__ float whh_m[NCOLS * HH];    //  8 KB
  __shared__ float kw1s[NKM * HH];       // 24 KB
  __shared__ float kw2s[NCOLS * K3H];    // 24 KB

  for (int i = tid; i < NCOLS * HH; i += 256) {
    int c = i >> 9, k = i & 511;
    whh_z[i] = Whh[(long)k * G2H + jz + c];
    whh_m[i] = Whh[(long)k * G2H + HH + jz + c];
  }
  for (int i = tid; i < NKM * HH; i += 256) {
    int c = i >> 9, k = i & 511;
    kw1s[i] = kW1[(long)k * K3H + jm + c];
  }
  for (int i = tid; i < NCOLS * K3H; i += 256) {
    int c = i / K3H, k = i - c * K3H;
    kw2s[i] = kW2[(long)k * HH + jz + c];
  }

  // persistent per-(row,col) state; valid in lanes 0..3 (lane = col offset)
  float A_own[4] = {0.f, 0.f, 0.f, 0.f};
  float c_own[4] = {0.f, 0.f, 0.f, 0.f};
  float M_own[4] = {0.f, 0.f, 0.f, 0.f};
  float inv_own[4] = {0.f, 0.f, 0.f, 0.f};
  float sreg[4];
  float A_base = 0.f, bz = 0.f, bm = 0.f, kb2r = 0.f;
  if (lane < NCOLS) {
    A_base = 1.f - expf(loglam[jz + lane]);
    bz   = bhh[jz + lane];
    bm   = bhh[HH + jz + lane];
    kb2r = kb2[jz + lane];
#pragma unroll
    for (int i = 0; i < 4; ++i)
      c_glob[(size_t)(rowbase + i) * HH + jz + lane] = 0.f;
  }
  const float kb1a = kb1[jm + (lane & 7)];
  const float kb1b = kb1[jm + 8 + (lane & 3)];

  // flag layout per group: GW arrival lines + 1 go line
  unsigned* arrive = flags + (size_t)g * (GW + 1) * FPAD;
  unsigned* goflag = arrive + (size_t)GW * FPAD;
  unsigned gen = 0;
  group_barrier(arrive, goflag, w, ++gen, tid);   // c zeros visible group-wide

  for (int it = 0; it <= LSEQ; ++it) {
    // gx prefetch (independent of barriers; scheduler hoists the loads)
    float gxz[4], gxm[4];
    if (it < LSEQ && lane < NCOLS) {
#pragma unroll
      for (int i = 0; i < 4; ++i) {
        const float* gxr = gx + ((size_t)(rowbase + i) * LSEQ + it) * G2H;
        gxz[i] = gxr[jz + lane];
        gxm[i] = gxr[HH + jz + lane];
      }
    }

    // ---- S1: sumsq(c_prev) -> s; g = h@W_hh; innov ----
    float az[NCOLS][4], am[NCOLS][4], ssp[4];
#pragma unroll
    for (int c = 0; c < NCOLS; ++c)
#pragma unroll
      for (int i = 0; i < 4; ++i) { az[c][i] = 0.f; am[c][i] = 0.f; }
#pragma unroll
    for (int i = 0; i < 4; ++i) ssp[i] = 0.f;

#pragma unroll
    for (int half = 0; half < 2; ++half) {
      float4 cv[4];
#pragma unroll
      for (int i = 0; i < 4; ++i)
        cv[i] = *(const float4*)(c_glob + (size_t)(rowbase + i) * HH +
                                 half * 256 + 4 * lane);
#pragma unroll
      for (int i = 0; i < 4; ++i) ssp[i] += dot4(cv[i], cv[i]);
#pragma unroll
      for (int c = 0; c < NCOLS; ++c) {
        float4 wz = *(const float4*)(&whh_z[c * HH + half * 256 + 4 * lane]);
        float4 wm = *(const float4*)(&whh_m[c * HH + half * 256 + 4 * lane]);
#pragma unroll
        for (int i = 0; i < 4; ++i) {
          az[c][i] += dot4(cv[i], wz);
          am[c][i] += dot4(cv[i], wm);
        }
      }
    }
#pragma unroll
    for (int i = 0; i < 4; ++i) {
      float a8[8];
#pragma unroll
      for (int c = 0; c < NCOLS; ++c) { a8[c] = az[c][i]; a8[4 + c] = am[c][i]; }
      float gsum = tree_reduce<8>(a8, lane);     // lane&7: 0..3=z, 4..7=m
      float ss = allreduce64(ssp[i]);
      float s = fminf(1.f, 10.f * rsqrtf(ss + 1e-6f));
      sreg[i] = s;
      float gmo = __shfl(gsum, NCOLS + (lane & 3), 64);
      if (it >= 1 && lane < NCOLS)
        hs[((size_t)(rowbase + i) * LSEQ + (it - 1)) * HH + jz + lane] =
            s * c_own[i];
      if (it < LSEQ && lane < NCOLS) {
        float gz = gsum * s + gxz[i] + bz;
        float gm = gmo * s + gxm[i] + bm;
        float Mv = tanhf(gm);
        float iv = gz - A_own[i] * (s * c_own[i]) - Mv;
        M_own[i] = Mv; inv_own[i] = iv;
        innov_glob[(size_t)(rowbase + i) * HH + jz + lane] = iv;
      }
    }
    if (it == LSEQ) break;
    group_barrier(arrive, goflag, w, ++gen, tid);

    // ---- S2: kmid = gelu(innov @ kW1 + kb1), 12 owned cols ----
    float bacc[NKM][4];
#pragma unroll
    for (int c = 0; c < NKM; ++c)
#pragma unroll
      for (int i = 0; i < 4; ++i) bacc[c][i] = 0.f;
#pragma unroll
    for (int half = 0; half < 2; ++half) {
      float4 iv4[4];
#pragma unroll
      for (int i = 0; i < 4; ++i)
        iv4[i] = *(const float4*)(innov_glob + (size_t)(rowbase + i) * HH +
                                  half * 256 + 4 * lane);
#pragma unroll
      for (int c = 0; c < NKM; ++c) {
        float4 w1 = *(const float4*)(&kw1s[c * HH + half * 256 + 4 * lane]);
#pragma unroll
        for (int i = 0; i < 4; ++i) bacc[c][i] += dot4(iv4[i], w1);
      }
    }
#pragma unroll
    for (int i = 0; i < 4; ++i) {
      float b8[8], b4[4];
#pragma unroll
      for (int c = 0; c < 8; ++c) b8[c] = bacc[c][i];
#pragma unroll
      for (int c = 0; c < 4; ++c) b4[c] = bacc[8 + c][i];
      float k1 = tree_reduce<8>(b8, lane);   // col jm + (lane&7)
      float k2 = tree_reduce<4>(b4, lane);   // col jm + 8 + (lane&3)
      if (lane < 8) {
        float xg = k1 + kb1a;
        kmid_glob[(size_t)(rowbase + i) * K3H + jm + lane] =
            0.5f * xg * (1.f + erff(xg * 0.7071067811865476f));
      }
      if (lane < 4) {
        float xg = k2 + kb1b;
        kmid_glob[(size_t)(rowbase + i) * K3H + jm + 8 + lane] =
            0.5f * xg * (1.f + erff(xg * 0.7071067811865476f));
      }
    }
    group_barrier(arrive, goflag, w, ++gen, tid);

    // ---- S3: K = tanh(kmid @ kW2 + kb2)*0.5 ; c update ----
    float racc[NCOLS][4];
#pragma unroll
    for (int c = 0; c < NCOLS; ++c)
#pragma unroll
      for (int i = 0; i < 4; ++i) racc[c][i] = 0.f;
#pragma unroll
    for (int chunk = 0; chunk < 6; ++chunk) {
      float4 mv[4];
#pragma unroll
      for (int i = 0; i < 4; ++i)
        mv[i] = *(const float4*)(kmid_glob + (size_t)(rowbase + i) * K3H +
                                 chunk * 256 + 4 * lane);
#pragma unroll
      for (int c = 0; c < NCOLS; ++c) {
        float4 w2 = *(const float4*)(&kw2s[c * K3H + chunk * 256 + 4 * lane]);
#pragma unroll
        for (int i = 0; i < 4; ++i) racc[c][i] += dot4(mv[i], w2);
      }
    }
#pragma unroll
    for (int i = 0; i < 4; ++i) {
      float r4[4];
#pragma unroll
      for (int c = 0; c < NCOLS; ++c) r4[c] = racc[c][i];
      float ksum = tree_reduce<4>(r4, lane);   // col jz + (lane&3)
      if (lane < NCOLS) {
        float Kv = tanhf(ksum + kb2r) * 0.5f;
        float An = A_base * (1.f - Kv * Kv);
        float cn = An * (sreg[i] * c_own[i]) + Kv * inv_own[i] + M_own[i];
        A_own[i] = An; c_own[i] = cn;
        c_glob[(size_t)(rowbase + i) * HH + jz + lane] = cn;
      }
    }
    group_barrier(arrive, goflag, w, ++gen, tid);
  }
}

// ---------------------------------------------------------------------------
// Workspace layout (bytes):
//   [0, 32M)    xn  (reused as hs after gx GEMM)
//   [32M, 96M)  gx
//   [96M,128M)  xmid (layer-1 output)
//   [128M, ..)  c(64KB) | innov(64KB) | kmid(192KB) | flags(~17KB padded)
// ---------------------------------------------------------------------------
extern "C" void kernel_launch(void* const* d_in, const int* in_sizes, int n_in,
                              void* d_out, int out_size, void* d_ws, size_t ws_size,
                              hipStream_t stream) {
  const float* x      = (const float*)d_in[0];
  const float* norm_w = (const float*)d_in[1];
  const float* W_ih   = (const float*)d_in[2];
  const float* b_ih   = (const float*)d_in[3];
  const float* W_hh   = (const float*)d_in[4];
  const float* b_hh   = (const float*)d_in[5];
  const float* loglam = (const float*)d_in[6];
  const float* kW1    = (const float*)d_in[7];
  const float* kb1    = (const float*)d_in[8];
  const float* kW2    = (const float*)d_in[9];
  const float* kb2    = (const float*)d_in[10];
  const float* Wo     = (const float*)d_in[11];
  float* out = (float*)d_out;

  char* ws = (char*)d_ws;
  float* xn   = (float*)(ws);
  float* gxb  = (float*)(ws + (size_t)33554432);
  float* xmid = (float*)(ws + (size_t)100663296);
  float* cbuf = (float*)(ws + (size_t)134217728);
  float* ibuf = cbuf + BB * HH;
  float* kbuf = ibuf + BB * HH;
  unsigned* flags = (unsigned*)(kbuf + BB * K3H);
  float* hs = xn;

  const size_t flag_bytes = (size_t)NGROUP * (GW + 1) * FPAD * sizeof(unsigned);

  for (int l = 0; l < 2; ++l) {
    const float* xin = l ? (const float*)xmid : x;
    float* cout = l ? out : xmid;

    rmsnorm_kernel<<<BB * LSEQ, 256, 0, stream>>>(xin, norm_w, xn);

    gemm_fp32<<<dim3(256, 16), 256, 0, stream>>>(
        xn, W_ih + (size_t)l * DD * G2H, b_ih + (size_t)l * G2H, gxb,
        BB * LSEQ, G2H, DD);

    hipMemsetAsync(flags, 0, flag_bytes, stream);
    scan_kernel<<<NGROUP * GW, 256, 0, stream>>>(
        gxb,
        W_hh + (size_t)l * HH * G2H, b_hh + (size_t)l * G2H,
        loglam + (size_t)l * HH,
        kW1 + (size_t)l * HH * K3H, kb1 + (size_t)l * K3H,
        kW2 + (size_t)l * K3H * HH, kb2 + (size_t)l * HH,
        cbuf, ibuf, kbuf, flags, hs);

    gemm_fp32<<<dim3(256, 8), 256, 0, stream>>>(
        hs, Wo + (size_t)l * HH * DD, nullptr, cout,
        BB * LSEQ, DD, HH);
  }
}

// Round 6
// 10644.270 us; speedup vs baseline: 5.9304x; 4.5328x over previous
//
#include <hip/hip_runtime.h>
#include <math.h>

// Problem constants (match reference)
#define BB   32
#define LSEQ 512
#define DD   512
#define HH   512
#define G2H  1024
#define K3H  1536

// Scan: 8 groups x 64 WGs (group = blk&7 — NO placement assumption; all comm
// goes through the memory-side Infinity Cache via explicit sc-flagged ops).
// Group g owns batch rows 4g..4g+3. WG slot s owns c/innov/K cols jz=8s..8s+7
// and kmid cols jm=24s..24s+23. WG = 256 thr = 4 waves; wave q owns col
// quarter (2 c-cols, 6 kmid-cols) x all 4 rows. 64 KB static LDS of f16
// weights => exactly 2 WGs/CU => all 512 co-resident (pigeonhole).
#define NG   8
#define GWG  64
#define FPAD 16

typedef unsigned int u32;
typedef _Float16 half2_t __attribute__((ext_vector_type(2)));
typedef u32 v4u __attribute__((ext_vector_type(4)));

// ---- coherence-point memory ops (same mechanism as the proven flag polls) --
__device__ __forceinline__ void mload4(v4u& d, const u32* p) {
  asm volatile("global_load_dwordx4 %0, %1, off sc1" : "=v"(d) : "v"(p));
}
// waitcnt that TIES the loaded regs so uses can't be scheduled before it
__device__ __forceinline__ void vmwait4(v4u& a, v4u& b, v4u& c, v4u& d) {
  asm volatile("s_waitcnt vmcnt(0)"
               : "+v"(a), "+v"(b), "+v"(c), "+v"(d) :: "memory");
}
__device__ __forceinline__ void mstore(u32* p, u32 v) {
  asm volatile("global_store_dword %0, %1, off sc0 sc1" :: "v"(p), "v"(v)
               : "memory");
}

__device__ __forceinline__ float dot2acc(u32 a, u32 b, float acc) {
#if __has_builtin(__builtin_amdgcn_fdot2)
  return __builtin_amdgcn_fdot2(__builtin_bit_cast(half2_t, a),
                                __builtin_bit_cast(half2_t, b), acc, false);
#else
  half2_t ha = __builtin_bit_cast(half2_t, a);
  half2_t hb = __builtin_bit_cast(half2_t, b);
  return acc + (float)ha[0] * (float)hb[0] + (float)ha[1] * (float)hb[1];
#endif
}
__device__ __forceinline__ float dotq(v4u a, v4u b, float acc) {
  acc = dot2acc(a.x, b.x, acc);
  acc = dot2acc(a.y, b.y, acc);
  acc = dot2acc(a.z, b.z, acc);
  acc = dot2acc(a.w, b.w, acc);
  return acc;
}
__device__ __forceinline__ u32 pkf16(float a, float b) {
#if __has_builtin(__builtin_amdgcn_cvt_pkrtz)
  return __builtin_bit_cast(u32, __builtin_amdgcn_cvt_pkrtz(a, b));
#else
  half2_t h; h[0] = (_Float16)a; h[1] = (_Float16)b;
  return __builtin_bit_cast(u32, h);
#endif
}

// In-register shuffle reduction trees (value for index lane&(M-1)).
template<int M> struct TreeC {
  static __device__ __forceinline__ void run(float* a, int lane, int d) {
    const bool hi = (lane & d) != 0;
#pragma unroll
    for (int i = 0; i < M / 2; ++i) {
      float mine  = hi ? a[2 * i + 1] : a[2 * i];
      float yours = hi ? a[2 * i]     : a[2 * i + 1];
      a[i] = mine + __shfl_xor(yours, d, 64);
    }
    TreeC<M / 2>::run(a, lane, d << 1);
  }
};
template<> struct TreeC<1> {
  static __device__ __forceinline__ void run(float*, int, int) {}
};
template<int M>
__device__ __forceinline__ float tree_reduce(float* a, int lane) {
  TreeC<M>::run(a, lane, 1);
  float v = a[0];
#pragma unroll
  for (int d = M; d <= 32; d <<= 1) v += __shfl_xor(v, d, 64);
  return v;
}

// ---------------------------------------------------------------------------
// Master-aggregated group barrier (R4-proven flags; zero cache maintenance —
// data coherence comes from sc-flagged data ops, not fences).
// ---------------------------------------------------------------------------
__device__ __forceinline__ void xbar(u32* arrive, u32* go, int slot,
                                     unsigned gen, int tid) {
  __syncthreads();   // drains vmcnt: all comm stores at coherence point
  if (slot == 0) {
    if (tid >= 1 && tid < GWG)
      while (__hip_atomic_load(&arrive[tid * FPAD], __ATOMIC_RELAXED,
                               __HIP_MEMORY_SCOPE_AGENT) < gen) {}
    __syncthreads();
    if (tid == 0) mstore(go, gen);
  } else {
    if (tid == 0) {
      mstore(&arrive[slot * FPAD], gen);
      while (__hip_atomic_load(go, __ATOMIC_RELAXED,
                               __HIP_MEMORY_SCOPE_AGENT) < gen) {}
    }
  }
  __syncthreads();
}

// ---------------------------------------------------------------------------
// RMSNorm: one 256-thread WG per row of 512.
// ---------------------------------------------------------------------------
__global__ __launch_bounds__(256)
void rmsnorm_kernel(const float* __restrict__ x, const float* __restrict__ w,
                    float* __restrict__ y)
{
  __shared__ float redl[256];
  const long row = blockIdx.x;
  const int t = threadIdx.x;
  const float* xr = x + row * DD;
  float v0 = xr[t], v1 = xr[t + 256];
  redl[t] = v0 * v0 + v1 * v1;
  __syncthreads();
  for (int off = 128; off > 0; off >>= 1) {
    if (t < off) redl[t] += redl[t + off];
    __syncthreads();
  }
  float scale = rsqrtf(redl[0] * (1.0f / 512.0f) + 1e-5f);
  float* yr = y + row * DD;
  yr[t]       = v0 * scale * w[t];
  yr[t + 256] = v1 * scale * w[t + 256];
}

// ---------------------------------------------------------------------------
// fp32 tiled GEMM: C[M,N] = A[M,K] @ B[K,N] (+ bias[n]), all row-major.
// ---------------------------------------------------------------------------
__global__ __launch_bounds__(256)
void gemm_fp32(const float* __restrict__ A, const float* __restrict__ B,
               const float* __restrict__ bias, float* __restrict__ C,
               int M, int N, int K)
{
  __shared__ float As[16][68];
  __shared__ float Bs[16][64];
  const int t  = threadIdx.x;
  const int tx = t & 15, ty = t >> 4;
  const long m0 = (long)blockIdx.x * 64;
  const long n0 = (long)blockIdx.y * 64;
  const int ar = t >> 2, ac = (t & 3) * 4;
  const int bk = t >> 4, bn = (t & 15) * 4;
  float acc[4][4] = {{0.f}};

  for (int k0 = 0; k0 < K; k0 += 16) {
    float4 av = *(const float4*)(A + (m0 + ar) * K + k0 + ac);
    float4 bv = *(const float4*)(B + (long)(k0 + bk) * N + n0 + bn);
    As[ac + 0][ar] = av.x; As[ac + 1][ar] = av.y;
    As[ac + 2][ar] = av.z; As[ac + 3][ar] = av.w;
    *(float4*)&Bs[bk][bn] = bv;
    __syncthreads();
#pragma unroll
    for (int kk = 0; kk < 16; ++kk) {
      float4 a = *(const float4*)&As[kk][ty * 4];
      float4 b = *(const float4*)&Bs[kk][tx * 4];
      acc[0][0] = fmaf(a.x, b.x, acc[0][0]); acc[0][1] = fmaf(a.x, b.y, acc[0][1]);
      acc[0][2] = fmaf(a.x, b.z, acc[0][2]); acc[0][3] = fmaf(a.x, b.w, acc[0][3]);
      acc[1][0] = fmaf(a.y, b.x, acc[1][0]); acc[1][1] = fmaf(a.y, b.y, acc[1][1]);
      acc[1][2] = fmaf(a.y, b.z, acc[1][2]); acc[1][3] = fmaf(a.y, b.w, acc[1][3]);
      acc[2][0] = fmaf(a.z, b.x, acc[2][0]); acc[2][1] = fmaf(a.z, b.y, acc[2][1]);
      acc[2][2] = fmaf(a.z, b.z, acc[2][2]); acc[2][3] = fmaf(a.z, b.w, acc[2][3]);
      acc[3][0] = fmaf(a.w, b.x, acc[3][0]); acc[3][1] = fmaf(a.w, b.y, acc[3][1]);
      acc[3][2] = fmaf(a.w, b.z, acc[3][2]); acc[3][3] = fmaf(a.w, b.w, acc[3][3]);
    }
    __syncthreads();
  }
  float4 bb = make_float4(0.f, 0.f, 0.f, 0.f);
  if (bias) bb = *(const float4*)(bias + n0 + tx * 4);
#pragma unroll
  for (int i = 0; i < 4; ++i) {
    float4 o;
    o.x = acc[i][0] + bb.x; o.y = acc[i][1] + bb.y;
    o.z = acc[i][2] + bb.z; o.w = acc[i][3] + bb.w;
    *(float4*)(C + (m0 + ty * 4 + i) * N + n0 + tx * 4) = o;
  }
}

// ---------------------------------------------------------------------------
// Persistent scan: 512 WGs x 256 thr, 64 KB static LDS (f16 weight pairs).
// State for (row r=L>>1, col jz+2q+(L&1)) lives in lanes L<8 of wave q.
// ---------------------------------------------------------------------------
__global__ __launch_bounds__(256)
void scan_kernel(const float* __restrict__ gx,
                 const float* __restrict__ Whh, const float* __restrict__ bhh,
                 const float* __restrict__ loglam,
                 const float* __restrict__ kW1, const float* __restrict__ kb1,
                 const float* __restrict__ kW2, const float* __restrict__ kb2,
                 u32* __restrict__ cpk, u32* __restrict__ ipk,
                 u32* __restrict__ kpk, u32* __restrict__ flags,
                 float* __restrict__ hs)
{
  const int blk  = blockIdx.x;
  const int g    = blk & 7;         // group (rows 4g..4g+3)
  const int s    = blk >> 3;        // slot 0..63
  const int tid  = threadIdx.x;
  const int q    = tid >> 6;        // wave 0..3
  const int lane = tid & 63;
  const int jz   = s * 8;
  const int jm   = s * 24;

  __shared__ u32 wh[16 * 256];      // 16 KB: 8 z-cols + 8 m-cols, f16 pairs
  __shared__ u32 w1s[24 * 256];     // 24 KB
  __shared__ u32 w2s[8 * 768];      // 24 KB  (total 64 KB)

  // ---- one-time weight staging (fp32 -> f16 pairs; pair p <-> k=2p,2p+1) ----
  for (int idx = tid; idx < 16 * 256; idx += 256) {
    int c = idx >> 8, p = idx & 255;
    int gcol = (c < 8) ? (jz + c) : (512 + jz + (c - 8));
    wh[idx] = pkf16(Whh[(size_t)(2 * p) * G2H + gcol],
                    Whh[(size_t)(2 * p + 1) * G2H + gcol]);
  }
  for (int idx = tid; idx < 24 * 256; idx += 256) {
    int c = idx >> 8, p = idx & 255;
    w1s[idx] = pkf16(kW1[(size_t)(2 * p) * K3H + jm + c],
                     kW1[(size_t)(2 * p + 1) * K3H + jm + c]);
  }
  for (int idx = tid; idx < 8 * 768; idx += 256) {
    int c = idx / 768, p = idx - c * 768;
    w2s[idx] = pkf16(kW2[(size_t)(2 * p) * HH + jz + c],
                     kW2[(size_t)(2 * p + 1) * HH + jz + c]);
  }

  // per-lane constants (state mapping: r=lane>>1, ci=lane&1, valid lanes<8)
  const int colA = jz + 2 * q + (lane & 1);
  const float Ab   = 1.f - expf(loglam[colA]);
  const float bz   = bhh[colA];
  const float bm   = bhh[512 + colA];
  const float kb2c = kb2[colA];
  int kb1i = lane & 7; if (kb1i > 5) kb1i = 5;
  const float kb1v = kb1[jm + 6 * q + kb1i];

  const int r_st  = (lane >> 1) & 3;
  const int growst = 4 * g + r_st;
  const size_t hsoff = (size_t)growst * LSEQ * HH + colA;
  const size_t gxoff = (size_t)growst * LSEQ * G2H + colA;

  const u32* crow[4]; const u32* irow[4]; const u32* krow[4];
#pragma unroll
  for (int r = 0; r < 4; ++r) {
    crow[r] = cpk + (size_t)(4 * g + r) * 256 + lane * 4;
    irow[r] = ipk + (size_t)(4 * g + r) * 256 + lane * 4;
    krow[r] = kpk + (size_t)(4 * g + r) * 768 + lane * 4;
  }
  u32* arrive = flags + (size_t)g * (GWG + 1) * FPAD;
  u32* goflag = arrive + (size_t)GWG * FPAD;

  // zero this WG's initial c slice (pairs 4s..4s+3 of rows 4g..4g+3)
  if (tid < 16) {
    int r = tid >> 2, j = tid & 3;
    mstore(cpk + (size_t)(4 * g + r) * 256 + 4 * s + j, 0u);
  }
  unsigned gen = 1;
  xbar(arrive, goflag, s, gen, tid);   // zeros + LDS staging visible

  float A_own = 0.f, c_own = 0.f, M_own = 0.f, I_own = 0.f, s_own = 1.f;

  for (int it = 0; it <= LSEQ; ++it) {
    // gx prefetch (cached, read-once)
    float gxz = 0.f, gxm = 0.f;
    if (lane < 8 && it < LSEQ) {
      gxz = gx[gxoff + (size_t)it * G2H];
      gxm = gx[gxoff + (size_t)it * G2H + 512];
    }

    // ---- S1: sumsq(c) -> s ; g = h@W_hh ; innov ----
    v4u cv0, cv1, cv2, cv3;
    mload4(cv0, crow[0]); mload4(cv1, crow[1]);
    mload4(cv2, crow[2]); mload4(cv3, crow[3]);
    vmwait4(cv0, cv1, cv2, cv3);
    float a4[4] = { dotq(cv0, cv0, 0.f), dotq(cv1, cv1, 0.f),
                    dotq(cv2, cv2, 0.f), dotq(cv3, cv3, 0.f) };
    float a16[16];
#pragma unroll
    for (int t = 0; t < 4; ++t) {          // t<2: z col 2q+t ; t>=2: m col
      int col = (t < 2) ? (2 * q + t) : (8 + 2 * q + (t - 2));
      v4u wq = *(const v4u*)(wh + col * 256 + lane * 4);
      a16[0 * 4 + t] = dotq(cv0, wq, 0.f);
      a16[1 * 4 + t] = dotq(cv1, wq, 0.f);
      a16[2 * 4 + t] = dotq(cv2, wq, 0.f);
      a16[3 * 4 + t] = dotq(cv3, wq, 0.f);
    }
    float ssv = tree_reduce<4>(a4, lane);     // row = lane&3
    float g16 = tree_reduce<16>(a16, lane);   // (r=(lane&15)>>2, t=lane&3)
    float sq  = __shfl(ssv, r_st, 64);
    float s_loc = fminf(1.f, 10.f * rsqrtf(sq + 1e-6f));
    float gz = __shfl(g16, (r_st * 4 + (lane & 1)) & 63, 64);
    float gm = __shfl(g16, (r_st * 4 + 2 + (lane & 1)) & 63, 64);
    if (lane < 8 && it >= 1)
      hs[hsoff + (size_t)(it - 1) * HH] = s_loc * c_own;
    if (it == LSEQ) break;
    float gzv = gz * s_loc + gxz + bz;
    float gmv = gm * s_loc + gxm + bm;
    float Mv = tanhf(gmv);
    float iv = gzv - A_own * (s_loc * c_own) - Mv;
    if (lane < 8) { M_own = Mv; I_own = iv; s_own = s_loc; }
    float ivn = __shfl(iv, (lane + 1) & 63, 64);
    if (lane < 8 && !(lane & 1))
      mstore(ipk + (size_t)growst * 256 + 4 * s + q, pkf16(iv, ivn));
    ++gen; xbar(arrive, goflag, s, gen, tid);

    // ---- S2: kmid = gelu(innov @ kW1 + kb1), 6 cols x 4 rows ----
    v4u iv0, iv1, iv2, iv3;
    mload4(iv0, irow[0]); mload4(iv1, irow[1]);
    mload4(iv2, irow[2]); mload4(iv3, irow[3]);
    vmwait4(iv0, iv1, iv2, iv3);
    float a32[32];
#pragma unroll
    for (int i = 0; i < 32; ++i) a32[i] = 0.f;
#pragma unroll
    for (int cc = 0; cc < 6; ++cc) {
      v4u wq = *(const v4u*)(w1s + (6 * q + cc) * 256 + lane * 4);
      a32[0 * 8 + cc] = dotq(iv0, wq, 0.f);
      a32[1 * 8 + cc] = dotq(iv1, wq, 0.f);
      a32[2 * 8 + cc] = dotq(iv2, wq, 0.f);
      a32[3 * 8 + cc] = dotq(iv3, wq, 0.f);
    }
    float t32 = tree_reduce<32>(a32, lane);   // (r=(lane&31)>>3, cc=lane&7)
    float kvb = t32 + kb1v;
    float gl = 0.5f * kvb * (1.f + erff(kvb * 0.7071067811865476f));
    float gln = __shfl(gl, (lane + 1) & 63, 64);
    if (lane < 32 && !(lane & 1) && (lane & 7) < 6) {
      int rr = (lane >> 3) & 3, cc = lane & 7;
      mstore(kpk + (size_t)(4 * g + rr) * 768 + 12 * s + 3 * q + (cc >> 1),
             pkf16(gl, gln));
    }
    ++gen; xbar(arrive, goflag, s, gen, tid);

    // ---- S3: K = tanh(kmid @ kW2 + kb2)*0.5 ; c update ----
    v4u k00,k01,k02, k10,k11,k12, k20,k21,k22, k30,k31,k32;
    mload4(k00, krow[0]); mload4(k01, krow[0]+256); mload4(k02, krow[0]+512);
    mload4(k10, krow[1]); mload4(k11, krow[1]+256); mload4(k12, krow[1]+512);
    mload4(k20, krow[2]); mload4(k21, krow[2]+256); mload4(k22, krow[2]+512);
    mload4(k30, krow[3]); mload4(k31, krow[3]+256); mload4(k32, krow[3]+512);
    vmwait4(k00, k01, k02, k10);
    vmwait4(k11, k12, k20, k21);
    vmwait4(k22, k30, k31, k32);
    float a8[8];
#pragma unroll
    for (int ci = 0; ci < 2; ++ci) {
      const u32* wc = w2s + (2 * q + ci) * 768 + lane * 4;
      v4u wq0 = *(const v4u*)(wc);
      v4u wq1 = *(const v4u*)(wc + 256);
      v4u wq2 = *(const v4u*)(wc + 512);
      a8[0 * 2 + ci] = dotq(k02, wq2, dotq(k01, wq1, dotq(k00, wq0, 0.f)));
      a8[1 * 2 + ci] = dotq(k12, wq2, dotq(k11, wq1, dotq(k10, wq0, 0.f)));
      a8[2 * 2 + ci] = dotq(k22, wq2, dotq(k21, wq1, dotq(k20, wq0, 0.f)));
      a8[3 * 2 + ci] = dotq(k32, wq2, dotq(k31, wq1, dotq(k30, wq0, 0.f)));
    }
    float kr = tree_reduce<8>(a8, lane);   // (r=(lane&7)>>1, ci=lane&1) = state map
    float Kv = tanhf(kr + kb2c) * 0.5f;
    float An = Ab * (1.f - Kv * Kv);
    float cn = An * (s_own * c_own) + Kv * I_own + M_own;
    if (lane < 8) { A_own = An; c_own = cn; }
    float cnn = __shfl(cn, (lane + 1) & 63, 64);
    if (lane < 8 && !(lane & 1))
      mstore(cpk + (size_t)growst * 256 + 4 * s + q, pkf16(cn, cnn));
    ++gen; xbar(arrive, goflag, s, gen, tid);
  }
}

// ---------------------------------------------------------------------------
// Workspace layout (bytes):
//   [0, 32M)    xn (reused as hs)
//   [32M, 96M)  gx
//   [96M,128M)  xmid
//   [128M, ..)  cpk 32K | ipk 32K | kpk 96K | flags 33K
// ---------------------------------------------------------------------------
extern "C" void kernel_launch(void* const* d_in, const int* in_sizes, int n_in,
                              void* d_out, int out_size, void* d_ws, size_t ws_size,
                              hipStream_t stream) {
  const float* x      = (const float*)d_in[0];
  const float* norm_w = (const float*)d_in[1];
  const float* W_ih   = (const float*)d_in[2];
  const float* b_ih   = (const float*)d_in[3];
  const float* W_hh   = (const float*)d_in[4];
  const float* b_hh   = (const float*)d_in[5];
  const float* loglam = (const float*)d_in[6];
  const float* kW1    = (const float*)d_in[7];
  const float* kb1    = (const float*)d_in[8];
  const float* kW2    = (const float*)d_in[9];
  const float* kb2    = (const float*)d_in[10];
  const float* Wo     = (const float*)d_in[11];
  float* out = (float*)d_out;

  char* ws = (char*)d_ws;
  float* xn   = (float*)(ws);
  float* gxb  = (float*)(ws + (size_t)33554432);
  float* xmid = (float*)(ws + (size_t)100663296);
  u32* cpk   = (u32*)(ws + (size_t)134217728);
  u32* ipk   = cpk + 8192;
  u32* kpk   = ipk + 8192;
  u32* flags = kpk + 24576;
  float* hs = xn;

  const size_t flag_bytes = (size_t)NG * (GWG + 1) * FPAD * sizeof(u32);

  for (int l = 0; l < 2; ++l) {
    const float* xin = l ? (const float*)xmid : x;
    float* cout = l ? out : xmid;

    rmsnorm_kernel<<<BB * LSEQ, 256, 0, stream>>>(xin, norm_w, xn);

    gemm_fp32<<<dim3(256, 16), 256, 0, stream>>>(
        xn, W_ih + (size_t)l * DD * G2H, b_ih + (size_t)l * G2H, gxb,
        BB * LSEQ, G2H, DD);

    hipMemsetAsync(flags, 0, flag_bytes, stream);
    scan_kernel<<<NG * GWG, 256, 0, stream>>>(
        gxb,
        W_hh + (size_t)l * HH * G2H, b_hh + (size_t)l * G2H,
        loglam + (size_t)l * HH,
        kW1 + (size_t)l * HH * K3H, kb1 + (size_t)l * K3H,
        kW2 + (size_t)l * K3H * HH, kb2 + (size_t)l * HH,
        cpk, ipk, kpk, flags, hs);

    gemm_fp32<<<dim3(256, 8), 256, 0, stream>>>(
        hs, Wo + (size_t)l * HH * DD, nullptr, cout,
        BB * LSEQ, DD, HH);
  }
}